// Round 2
// baseline (9284.006 us; speedup 1.0000x reference)
//
#include <hip/hip_runtime.h>

typedef unsigned short ushort_t;
typedef unsigned int   uint_t;
typedef __attribute__((ext_vector_type(8))) short  bf16x8;
typedef __attribute__((ext_vector_type(4))) float  f32x4;

#define B_      32
#define TIN_    128
#define TOUT_   500
#define R_      5
#define STEPS_  100
#define MEL_    128
#define SPEC_   513
#define NWG_    32

// ---------------- ws layout (bytes) ----------------
// zeroed each launch:
#define ZB_SLOTS   0          // 32*64 int
#define ZB_AH      8192       // [32][256] bf16  h_att
#define ZB_ARH     24576      // [32][256] bf16  r*h_att
#define ZB_AHC     40960      // [32][512] bf16  [h_att | ctx]
#define ZB_AXH1    73728      // [32][512] bf16  [aco | h1]
#define ZB_AXRH1   106496     // [32][512] bf16  [aco | r*h1]
#define ZB_AY1H2   139264     // [32][512] bf16  [y1 | h2]
#define ZB_AY1RH2  172032     // [32][512] bf16  [y1 | r*h2]
#define ZB_QBUF    204800     // [32][256] bf16  qW
#define ZB_UBUF    221184     // [32][256] f32   u gates att
#define ZB_U1BUF   253952     // [32][256] f32
#define ZB_U2BUF   286720     // [32][256] f32
#define ZB_EBUF    319488     // [32][128] f32   attn scores
#define ZB_QSBUF   335872     // [32][2] f32 (padded)
#define ZB_HF      336896     // [32][256] f32 h_att master
#define ZB_H1F     369664
#define ZB_H2F     402432
#define ZB_ACOF    435200
#define ZB_Y1F     467968
#define ZB_END     500736
// written by prep kernels:
#define OFF_SPK2    501760    // 32*32 f32
#define OFF_ACOSPK2 505856    // 32*256 f32
#define OFF_MS2     538624    // 20 f32
#define OFF_KS2     539136    // 20 f32
#define OFF_PREG2   539648    // 100*32*512 f32
#define OFF_PREC2   7093248   // 100*32*256 f32
#define OFF_Y2G     10370048  // 100*32*256 f32
#define OFF_KEYSP   13646848  // [32 wg][32 b][4 t][256] bf16
#define OFF_ENCP    15744000  // [32 wg][32 b][128 t][8] bf16
// end 17,841,152

// ---------------- helpers ----------------
__device__ __forceinline__ float bf1(ushort_t u){ return __uint_as_float(((uint_t)u) << 16); }
__device__ __forceinline__ ushort_t f2bf(float f){
    uint_t b = __float_as_uint(f);
    uint_t r = (b + 0x7fffu + ((b >> 16) & 1u)) >> 16;
    return (ushort_t)r;
}
__device__ __forceinline__ float fexp2(float x){ return __builtin_amdgcn_exp2f(x); }
__device__ __forceinline__ float frcp(float x){ return __builtin_amdgcn_rcpf(x); }
__device__ __forceinline__ float sigm_f(float x){ return frcp(1.f + fexp2(-1.44269504f * x)); }
__device__ __forceinline__ float tanh_f(float x){
    float e = fexp2(2.88539008f * x);
    return 1.f - 2.f * frcp(e + 1.f);
}

// ---------------- K1: tiny constants ----------------
__global__ __launch_bounds__(256) void k_small(
    const float* __restrict__ st, const float* __restrict__ Ws_pre,
    const float* __restrict__ bs_pre, const float* __restrict__ Wk_s,
    const float* __restrict__ spk_embed, const int* __restrict__ speaker,
    const float* __restrict__ Wa, const float* __restrict__ ba,
    float* __restrict__ spk_sel, float* __restrict__ aco_spk,
    float* __restrict__ ms_g, float* __restrict__ ks_g)
{
    __shared__ float spk_l[B_*32];
    __shared__ float ms_l[20];
    const int tid = threadIdx.x;
    for(int i=tid; i<B_*32; i+=256){
        int b = i >> 5, j = i & 31;
        float v = spk_embed[speaker[b]*32 + j];
        spk_l[i] = v; spk_sel[i] = v;
    }
    if(tid < 20){
        int n = tid >> 1, j = tid & 1;
        float v = st[n*2]*Ws_pre[j] + st[n*2+1]*Ws_pre[2+j] + bs_pre[j];
        v = fmaxf(v, 0.f);
        ms_l[tid] = v; ms_g[tid] = v;
    }
    __syncthreads();
    if(tid < 20){
        int n = tid >> 1, j = tid & 1;
        ks_g[tid] = ms_l[n*2]*Wk_s[j] + ms_l[n*2+1]*Wk_s[2+j];
    }
    for(int i=tid; i<B_*256; i+=256){
        int b = i >> 8, n = i & 255;
        float acc = ba[n];
        #pragma unroll
        for(int k=0;k<32;++k) acc = fmaf(spk_l[b*32+k], Wa[(256+k)*256 + n], acc);
        aco_spk[i] = acc;
    }
}

// ---------------- K4: keys = enc @ Wk -> bf16 permuted for scan ----------------
__global__ __launch_bounds__(256) void k_keys(const float* __restrict__ enc,
                                              const float* __restrict__ Wk,
                                              ushort_t* __restrict__ keysp){
    __shared__ float x16[16][256];
    const int bid = blockIdx.x;      // 256 = 32 b * 8 tgroups
    const int b = bid >> 3, tg = bid & 7, t0 = tg*16;
    const int tid = threadIdx.x;
    for(int i=tid; i<16*256; i+=256){
        int r = i >> 8, k = i & 255;
        x16[r][k] = enc[((size_t)b*TIN_ + t0 + r)*256 + k];
    }
    __syncthreads();
    float acc[16];
    #pragma unroll
    for(int r=0;r<16;++r) acc[r] = 0.f;
    for(int k=0;k<256;++k){
        float w = Wk[k*256 + tid];
        #pragma unroll
        for(int r=0;r<16;++r) acc[r] = fmaf(x16[r][k], w, acc[r]);
    }
    #pragma unroll
    for(int r=0;r<16;++r){
        int t = t0 + r;
        keysp[((size_t)((t>>2)*32 + b)*4 + (t&3))*256 + tid] = f2bf(acc[r]);
    }
}

// ---------------- enc permute: enc_p[d>>3][b][t][d&7] ----------------
__global__ __launch_bounds__(256) void k_encperm(const float* __restrict__ enc,
                                                 ushort_t* __restrict__ encp){
    int o = blockIdx.x*256 + threadIdx.x;      // 4096 blocks -> 1,048,576
    int j = o & 7, t = (o>>3) & 127, b = (o>>10) & 31, wg = o >> 15;
    encp[o] = f2bf(enc[((size_t)b*TIN_ + t)*256 + wg*8 + j]);
}

// ---------------- K3: prenet + x-part of att-GRU for all steps ----------------
__global__ __launch_bounds__(256) void k_prenet(
    const float* __restrict__ mg, const float* __restrict__ spk_sel,
    const float* __restrict__ Wp1, const float* __restrict__ bp1,
    const float* __restrict__ Wp2, const float* __restrict__ bp2,
    const float* __restrict__ Wg_att, const float* __restrict__ bg_att,
    const float* __restrict__ Wc_att, const float* __restrict__ bc_att,
    float* __restrict__ preg, float* __restrict__ prec)
{
    __shared__ float fr[16][128];
    __shared__ float p1[16][256];
    __shared__ float p2[16][128];
    __shared__ float spk_l[16][32];
    const int r0 = blockIdx.x * 16;     // 200 blocks * 16 rows = 3200 (s*32+b)
    const int tid = threadIdx.x;
    for(int i=tid; i<16*128; i+=256){
        int r = i >> 7, mcol = i & 127;
        int row = r0 + r, s = row >> 5, b = row & 31;
        fr[r][mcol] = (s == 0) ? 0.f : mg[((size_t)b*TOUT_ + s*R_ - 1)*MEL_ + mcol];
    }
    for(int i=tid; i<16*32; i+=256){
        int r = i >> 5, j = i & 31;
        spk_l[r][j] = spk_sel[((r0 + r) & 31)*32 + j];
    }
    __syncthreads();
    {
        float acc[16];
        #pragma unroll
        for(int r=0;r<16;++r) acc[r]=0.f;
        for(int k=0;k<128;++k){
            float w = Wp1[k*256 + tid];
            #pragma unroll
            for(int r=0;r<16;++r) acc[r] = fmaf(fr[r][k], w, acc[r]);
        }
        float bb = bp1[tid];
        #pragma unroll
        for(int r=0;r<16;++r) p1[r][tid] = fmaxf(acc[r] + bb, 0.f);
    }
    __syncthreads();
    if(tid < 128){
        float acc[16];
        #pragma unroll
        for(int r=0;r<16;++r) acc[r]=0.f;
        for(int k=0;k<256;++k){
            float w = Wp2[k*128 + tid];
            #pragma unroll
            for(int r=0;r<16;++r) acc[r] = fmaf(p1[r][k], w, acc[r]);
        }
        float bb = bp2[tid];
        #pragma unroll
        for(int r=0;r<16;++r) p2[r][tid] = fmaxf(acc[r] + bb, 0.f);
    }
    __syncthreads();
    {
        float aA[16], aB[16];
        #pragma unroll
        for(int r=0;r<16;++r){ aA[r]=0.f; aB[r]=0.f; }
        for(int k=0;k<128;++k){
            float wA = Wg_att[k*512 + tid], wB = Wg_att[k*512 + tid + 256];
            #pragma unroll
            for(int r=0;r<16;++r){ float pv = p2[r][k]; aA[r]=fmaf(pv,wA,aA[r]); aB[r]=fmaf(pv,wB,aB[r]); }
        }
        for(int k=0;k<32;++k){
            float wA = Wg_att[(128+k)*512 + tid], wB = Wg_att[(128+k)*512 + tid + 256];
            #pragma unroll
            for(int r=0;r<16;++r){ float sv = spk_l[r][k]; aA[r]=fmaf(sv,wA,aA[r]); aB[r]=fmaf(sv,wB,aB[r]); }
        }
        float bA = bg_att[tid], bB = bg_att[tid + 256];
        #pragma unroll
        for(int r=0;r<16;++r){
            preg[(size_t)(r0+r)*512 + tid]       = aA[r] + bA;
            preg[(size_t)(r0+r)*512 + tid + 256] = aB[r] + bB;
        }
    }
    {
        float acc[16];
        #pragma unroll
        for(int r=0;r<16;++r) acc[r]=0.f;
        for(int k=0;k<128;++k){
            float w = Wc_att[k*256 + tid];
            #pragma unroll
            for(int r=0;r<16;++r) acc[r] = fmaf(p2[r][k], w, acc[r]);
        }
        for(int k=0;k<32;++k){
            float w = Wc_att[(128+k)*256 + tid];
            #pragma unroll
            for(int r=0;r<16;++r) acc[r] = fmaf(spk_l[r][k], w, acc[r]);
        }
        float bb = bc_att[tid];
        #pragma unroll
        for(int r=0;r<16;++r) prec[(size_t)(r0+r)*256 + tid] = acc[r] + bb;
    }
}

// ---------------- cooperative scan helpers ----------------
__device__ __forceinline__ void gridbar(int* slots, int p, int seq, int tid){
    __threadfence();
    __syncthreads();
    if(tid == 0) __hip_atomic_store(&slots[p*64], seq, __ATOMIC_RELEASE, __HIP_MEMORY_SCOPE_AGENT);
    if(tid < NWG_){
        while(__hip_atomic_load(&slots[tid*64], __ATOMIC_ACQUIRE, __HIP_MEMORY_SCOPE_AGENT) < seq){}
    }
    __syncthreads();
}

// load weight col-slice (bf16, col-major [16][Ktot], XOR-swizzled) into LDS
__device__ __forceinline__ void loadW(const float* W, int ldw, int rowbase, int nk, int kbase,
                                      int Ktot, int col0, int ncols, ushort_t* lds, int tid){
    for(int e = tid; e < 16*nk; e += 512){
        int col = e & 15, k = e >> 4;
        ushort_t v = 0;
        if(col < ncols) v = f2bf(W[(size_t)(rowbase + k)*ldw + col0 + col]);
        lds[(col*Ktot + kbase + k) ^ ((col & 7) << 3)] = v;
    }
}

// GEMM: C[32][Ns] += A[32][K] (global bf16) * W (LDS [16][K] colmajor swz)
// wave w: m = w&1 (rows m*16..m*16+16), kq = w>>1 (K quarter). kq0 waves get full sum.
template<int K>
__device__ __forceinline__ f32x4 do_gemm(const ushort_t* Ab, const ushort_t* Wl, float* red,
                                         int m, int kq, int lane){
    f32x4 acc = {0.f,0.f,0.f,0.f};
    const int row = m*16 + (lane & 15);
    const int col = lane & 15;
    const int ko  = (lane >> 4) * 8;
    #pragma unroll
    for(int t = 0; t < K/128; ++t){
        const int k0 = kq*(K/4) + t*32 + ko;
        bf16x8 a = *reinterpret_cast<const bf16x8*>(Ab + row*K + k0);
        bf16x8 b = *reinterpret_cast<const bf16x8*>(Wl + ((col*K + k0) ^ ((col & 7) << 3)));
        acc = __builtin_amdgcn_mfma_f32_16x16x32_bf16(a, b, acc, 0, 0, 0);
    }
    if(kq > 0) *reinterpret_cast<f32x4*>(red + ((kq-1)*2 + m)*256 + lane*4) = acc;
    __syncthreads();
    if(kq == 0){
        #pragma unroll
        for(int j = 0; j < 3; ++j)
            acc += *reinterpret_cast<const f32x4*>(red + (j*2 + m)*256 + lane*4);
    }
    return acc;
}

// ---------------- K5: the cooperative scan ----------------
__global__ __launch_bounds__(512) void k_scan_coop(
    char* ws,
    const float* __restrict__ Wg_att, const float* __restrict__ Wc_att,
    const float* __restrict__ Wq, const float* __restrict__ Wq_s,
    const float* __restrict__ v_att, const float* __restrict__ v_s,
    const float* __restrict__ Wa,
    const float* __restrict__ Wg1, const float* __restrict__ Wc1,
    const float* __restrict__ Wg2, const float* __restrict__ Wc2,
    const float* __restrict__ bg1, const float* __restrict__ bc1,
    const float* __restrict__ bg2, const float* __restrict__ bc2,
    const int* __restrict__ inp_mask, float* __restrict__ out_alpha)
{
    const int p = blockIdx.x, tid = threadIdx.x;
    const int lane = tid & 63, wv = tid >> 6;
    const int m = wv & 1, kq = wv >> 1;

    int* slots      = (int*)(ws + ZB_SLOTS);
    ushort_t* A_h    = (ushort_t*)(ws + ZB_AH);
    ushort_t* A_rh   = (ushort_t*)(ws + ZB_ARH);
    ushort_t* A_hc   = (ushort_t*)(ws + ZB_AHC);
    ushort_t* A_xh1  = (ushort_t*)(ws + ZB_AXH1);
    ushort_t* A_xrh1 = (ushort_t*)(ws + ZB_AXRH1);
    ushort_t* A_y1h2 = (ushort_t*)(ws + ZB_AY1H2);
    ushort_t* A_y1rh2= (ushort_t*)(ws + ZB_AY1RH2);
    ushort_t* Qbuf   = (ushort_t*)(ws + ZB_QBUF);
    float* ubuf  = (float*)(ws + ZB_UBUF);
    float* u1buf = (float*)(ws + ZB_U1BUF);
    float* u2buf = (float*)(ws + ZB_U2BUF);
    float* ebuf  = (float*)(ws + ZB_EBUF);
    float* qsbuf = (float*)(ws + ZB_QSBUF);
    float* hf    = (float*)(ws + ZB_HF);
    float* h1f   = (float*)(ws + ZB_H1F);
    float* h2f   = (float*)(ws + ZB_H2F);
    float* acof  = (float*)(ws + ZB_ACOF);
    float* y1f   = (float*)(ws + ZB_Y1F);
    const float* acospk = (const float*)(ws + OFF_ACOSPK2);
    const float* msg    = (const float*)(ws + OFF_MS2);
    const float* ksg    = (const float*)(ws + OFF_KS2);
    const float* preg   = (const float*)(ws + OFF_PREG2);
    const float* prec   = (const float*)(ws + OFF_PREC2);
    float* y2g          = (float*)(ws + OFF_Y2G);
    const ushort_t* keysp = (const ushort_t*)(ws + OFF_KEYSP);
    const ushort_t* encp  = (const ushort_t*)(ws + OFF_ENCP);

    // LDS: resident weight slices (col-major [16][K], bf16, swizzled)
    __shared__ ushort_t wA[16*256], wB[16*256], wC[16*256];
    __shared__ ushort_t wG[16*512], wH[16*512], wI[16*512], wJ[16*512], wK[16*512];
    __shared__ __align__(16) char uni[16384];     // union: red (6KB f32) | qlds (16KB bf16)
    float* red = (float*)uni;
    ushort_t* qlds = (ushort_t*)uni;
    __shared__ float vatt_l[256];
    __shared__ float msks[48];
    __shared__ float ctxs_l[64];

    loadW(Wg_att, 512, 160, 256, 0, 256, p*16, 16, wA, tid);
    loadW(Wc_att, 256, 160, 256, 0, 256, p*8,  8,  wB, tid);
    loadW(Wq,     256, 0,   256, 0, 256, p*8,  8,  wC, tid);
    loadW(Wa,     256, 0,   256, 0,   512, p*8, 8, wG, tid);   // rows 0..255  (h)
    loadW(Wa,     256, 288, 256, 256, 512, p*8, 8, wG, tid);   // rows 288..543 (ctx)
    loadW(Wg1,    512, 0,   512, 0, 512, p*16, 16, wH, tid);
    loadW(Wc1,    256, 0,   512, 0, 512, p*8,  8,  wI, tid);
    loadW(Wg2,    512, 0,   512, 0, 512, p*16, 16, wJ, tid);
    loadW(Wc2,    256, 0,   512, 0, 512, p*8,  8,  wK, tid);
    if(tid < 256) vatt_l[tid] = v_att[tid];
    if(tid < 20) msks[tid] = msg[tid];
    if(tid >= 20 && tid < 40) msks[tid] = ksg[tid-20];
    if(tid == 40) msks[40] = v_s[0];
    if(tid == 41) msks[41] = v_s[1];
    __syncthreads();

    int seq = 0;
    for(int s = 0; s < STEPS_; ++s){
        const int sb = s*32;
        // ---- A: att-GRU gates ----
        __syncthreads();   // guard red WAR vs stage K of prev step
        f32x4 acc = do_gemm<256>(A_h, wA, red, m, kq, lane);
        if(kq == 0){
            int col = lane & 15, gcol = p*16 + col;
            #pragma unroll
            for(int r=0;r<4;++r){
                int b = m*16 + ((lane>>4)<<2) + r;
                float g = sigm_f(acc[r] + preg[(size_t)(sb + b)*512 + gcol]);
                if(p < 16) A_rh[b*256 + gcol] = f2bf(g * hf[b*256 + gcol]);
                else       ubuf[b*256 + gcol - 256] = g;
            }
        }
        gridbar(slots, p, ++seq, tid);
        // ---- B: att-GRU candidate + h update ----
        acc = do_gemm<256>(A_rh, wB, red, m, kq, lane);
        if(kq == 0 && (lane & 15) < 8){
            int gcol = p*8 + (lane & 15);
            #pragma unroll
            for(int r=0;r<4;++r){
                int b = m*16 + ((lane>>4)<<2) + r;
                float cc = tanh_f(acc[r] + prec[(size_t)(sb + b)*256 + gcol]);
                float u  = ubuf[b*256 + gcol];
                float hn = u*hf[b*256 + gcol] + (1.f - u)*cc;
                hf[b*256 + gcol] = hn;
                ushort_t hb = f2bf(hn);
                A_h[b*256 + gcol] = hb;
                A_hc[b*512 + gcol] = hb;
            }
        }
        gridbar(slots, p, ++seq, tid);
        // ---- C: qW = h @ Wq (+ style query on p0) ----
        acc = do_gemm<256>(A_h, wC, red, m, kq, lane);
        if(kq == 0 && (lane & 15) < 8){
            int gcol = p*8 + (lane & 15);
            #pragma unroll
            for(int r=0;r<4;++r){
                int b = m*16 + ((lane>>4)<<2) + r;
                Qbuf[b*256 + gcol] = f2bf(acc[r]);
            }
        }
        if(p == 0){
            int b = tid >> 4, i = tid & 15;
            float q0 = 0.f, q1 = 0.f;
            #pragma unroll
            for(int kk=0; kk<16; ++kk){
                int k = i*16 + kk;
                float hv = hf[b*256 + k];
                q0 = fmaf(hv, Wq_s[k*2],   q0);
                q1 = fmaf(hv, Wq_s[k*2+1], q1);
            }
            #pragma unroll
            for(int d=1; d<16; d<<=1){ q0 += __shfl_xor(q0,d,64); q1 += __shfl_xor(q1,d,64); }
            if(i == 0){ qsbuf[b*2] = q0; qsbuf[b*2+1] = q1; }
        }
        gridbar(slots, p, ++seq, tid);
        // ---- D: attention scores (t-slice of 4 per WG) ----
        ((bf16x8*)qlds)[tid]       = ((const bf16x8*)Qbuf)[tid];
        ((bf16x8*)qlds)[tid + 512] = ((const bf16x8*)Qbuf)[tid + 512];
        __syncthreads();
        {
            int b = tid >> 4, tl = (tid >> 2) & 3, q = tid & 3;
            int tg = p*4 + tl;
            const ushort_t* kp = keysp + (((size_t)p*32 + b)*4 + tl)*256 + q*64;
            const ushort_t* qp = qlds + b*256 + q*64;
            float e = 0.f;
            #pragma unroll
            for(int i=0;i<8;++i){
                bf16x8 kv = *(const bf16x8*)(kp + i*8);
                bf16x8 qv = *(const bf16x8*)(qp + i*8);
                #pragma unroll
                for(int j=0;j<8;++j){
                    int a = q*64 + i*8 + j;
                    e = fmaf(vatt_l[a], tanh_f(bf1((ushort_t)kv[j]) + bf1((ushort_t)qv[j])), e);
                }
            }
            e += __shfl_xor(e, 1, 64); e += __shfl_xor(e, 2, 64);
            if(q == 0) ebuf[b*128 + tg] = (tg < inp_mask[b]) ? e : -1e9f;
        }
        gridbar(slots, p, ++seq, tid);
        // ---- E: redundant softmax + context col-slice + style ctx ----
        {
            int b = tid >> 4, i = tid & 15;
            f32x4 e0 = *(const f32x4*)(ebuf + b*128 + i*8);
            f32x4 e1 = *(const f32x4*)(ebuf + b*128 + i*8 + 4);
            float mx = fmaxf(fmaxf(fmaxf(e0[0],e0[1]),fmaxf(e0[2],e0[3])),
                             fmaxf(fmaxf(e1[0],e1[1]),fmaxf(e1[2],e1[3])));
            #pragma unroll
            for(int d=1; d<16; d<<=1) mx = fmaxf(mx, __shfl_xor(mx,d,64));
            float a8[8]; float sum = 0.f;
            #pragma unroll
            for(int j=0;j<8;++j){
                float ev = (j<4)? e0[j] : e1[j-4];
                a8[j] = fexp2((ev - mx)*1.44269504f);
                sum += a8[j];
            }
            #pragma unroll
            for(int d=1; d<16; d<<=1) sum += __shfl_xor(sum,d,64);
            float inv = frcp(sum);
            #pragma unroll
            for(int j=0;j<8;++j) a8[j] *= inv;
            if(p == 1){
                float* oa = out_alpha + ((size_t)b*STEPS_ + s)*TIN_ + i*8;
                #pragma unroll
                for(int j=0;j<8;++j) oa[j] = a8[j];
            }
            float cj[8] = {0,0,0,0,0,0,0,0};
            const ushort_t* ep = encp + (((size_t)p*32 + b)*128 + i*8)*8;
            #pragma unroll
            for(int t2=0;t2<8;++t2){
                bf16x8 ev = *(const bf16x8*)(ep + t2*8);
                #pragma unroll
                for(int j=0;j<8;++j) cj[j] = fmaf(a8[t2], bf1((ushort_t)ev[j]), cj[j]);
            }
            #pragma unroll
            for(int d=1; d<16; d<<=1){
                #pragma unroll
                for(int j=0;j<8;++j) cj[j] += __shfl_xor(cj[j],d,64);
            }
            if(i == 0){
                bf16x8 pk;
                #pragma unroll
                for(int j=0;j<8;++j) pk[j] = (short)f2bf(cj[j]);
                *(bf16x8*)(A_hc + b*512 + 256 + p*8) = pk;
            }
        }
        if(tid < 32){
            int b = tid;
            float q0 = qsbuf[b*2], q1 = qsbuf[b*2+1];
            float es[10]; float mx = -1e30f;
            #pragma unroll
            for(int n=0;n<10;++n){
                float t = msks[40]*tanh_f(msks[20+n*2] + q0) + msks[41]*tanh_f(msks[20+n*2+1] + q1);
                es[n] = t; mx = fmaxf(mx, t);
            }
            float sum = 0.f;
            #pragma unroll
            for(int n=0;n<10;++n){ float pe = fexp2((es[n]-mx)*1.44269504f); es[n]=pe; sum += pe; }
            float inv = frcp(sum); float c0=0.f, c1=0.f;
            #pragma unroll
            for(int n=0;n<10;++n){ float al = es[n]*inv; c0 = fmaf(al, msks[n*2], c0); c1 = fmaf(al, msks[n*2+1], c1); }
            ctxs_l[b*2] = c0; ctxs_l[b*2+1] = c1;
        }
        gridbar(slots, p, ++seq, tid);
        // ---- G: aco = [h|ctx]@Wa + acospk + ctx_s@Wa_s ----
        acc = do_gemm<512>(A_hc, wG, red, m, kq, lane);
        if(kq == 0 && (lane & 15) < 8){
            int gcol = p*8 + (lane & 15);
            #pragma unroll
            for(int r=0;r<4;++r){
                int b = m*16 + ((lane>>4)<<2) + r;
                float v = acc[r] + acospk[b*256 + gcol]
                        + ctxs_l[b*2]   * Wa[(size_t)544*256 + gcol]
                        + ctxs_l[b*2+1] * Wa[(size_t)545*256 + gcol];
                acof[b*256 + gcol] = v;
                ushort_t vb = f2bf(v);
                A_xh1[b*512 + gcol] = vb;
                A_xrh1[b*512 + gcol] = vb;
            }
        }
        gridbar(slots, p, ++seq, tid);
        // ---- H: GRU1 gates ----
        acc = do_gemm<512>(A_xh1, wH, red, m, kq, lane);
        if(kq == 0){
            int gcol = p*16 + (lane & 15);
            #pragma unroll
            for(int r=0;r<4;++r){
                int b = m*16 + ((lane>>4)<<2) + r;
                float g = sigm_f(acc[r] + bg1[gcol]);
                if(p < 16) A_xrh1[b*512 + 256 + gcol] = f2bf(g * h1f[b*256 + gcol]);
                else       u1buf[b*256 + gcol - 256] = g;
            }
        }
        gridbar(slots, p, ++seq, tid);
        // ---- I: GRU1 candidate + y1 ----
        acc = do_gemm<512>(A_xrh1, wI, red, m, kq, lane);
        if(kq == 0 && (lane & 15) < 8){
            int gcol = p*8 + (lane & 15);
            #pragma unroll
            for(int r=0;r<4;++r){
                int b = m*16 + ((lane>>4)<<2) + r;
                float cc = tanh_f(acc[r] + bc1[gcol]);
                float u  = u1buf[b*256 + gcol];
                float hn = u*h1f[b*256 + gcol] + (1.f - u)*cc;
                h1f[b*256 + gcol] = hn;
                A_xh1[b*512 + 256 + gcol] = f2bf(hn);
                float y1 = hn + acof[b*256 + gcol];
                y1f[b*256 + gcol] = y1;
                ushort_t yb = f2bf(y1);
                A_y1h2[b*512 + gcol] = yb;
                A_y1rh2[b*512 + gcol] = yb;
            }
        }
        gridbar(slots, p, ++seq, tid);
        // ---- J: GRU2 gates ----
        acc = do_gemm<512>(A_y1h2, wJ, red, m, kq, lane);
        if(kq == 0){
            int gcol = p*16 + (lane & 15);
            #pragma unroll
            for(int r=0;r<4;++r){
                int b = m*16 + ((lane>>4)<<2) + r;
                float g = sigm_f(acc[r] + bg2[gcol]);
                if(p < 16) A_y1rh2[b*512 + 256 + gcol] = f2bf(g * h2f[b*256 + gcol]);
                else       u2buf[b*256 + gcol - 256] = g;
            }
        }
        gridbar(slots, p, ++seq, tid);
        // ---- K: GRU2 candidate + y2 (no barrier; next stage A doesn't conflict) ----
        acc = do_gemm<512>(A_y1rh2, wK, red, m, kq, lane);
        if(kq == 0 && (lane & 15) < 8){
            int gcol = p*8 + (lane & 15);
            #pragma unroll
            for(int r=0;r<4;++r){
                int b = m*16 + ((lane>>4)<<2) + r;
                float cc = tanh_f(acc[r] + bc2[gcol]);
                float u  = u2buf[b*256 + gcol];
                float hn = u*h2f[b*256 + gcol] + (1.f - u)*cc;
                h2f[b*256 + gcol] = hn;
                A_y1h2[b*512 + 256 + gcol] = f2bf(hn);
                y2g[((size_t)sb + b)*256 + gcol] = hn + y1f[b*256 + gcol];
            }
        }
    }
}

// ---------------- K6: output_mel = y2 @ Wo + bo ----------------
__global__ __launch_bounds__(256) void k_omel(const float* __restrict__ y2g,
                                              const float* __restrict__ Wo,
                                              const float* __restrict__ bo,
                                              float* __restrict__ out_mel){
    __shared__ float y8[8][256];
    const int r0 = blockIdx.x * 8;
    const int tid = threadIdx.x;
    for(int i=tid; i<8*256; i+=256){ int r=i>>8, k=i&255; y8[r][k] = y2g[(size_t)(r0+r)*256 + k]; }
    __syncthreads();
    float aA[8], aB[8], aC[8];
    #pragma unroll
    for(int r=0;r<8;++r){ aA[r]=0.f; aB[r]=0.f; aC[r]=0.f; }
    for(int k=0;k<256;++k){
        float wA = Wo[(size_t)k*640 + tid];
        float wB = Wo[(size_t)k*640 + tid + 256];
        float wC = (tid < 128) ? Wo[(size_t)k*640 + tid + 512] : 0.f;
        #pragma unroll
        for(int r=0;r<8;++r){
            float yv = y8[r][k];
            aA[r]=fmaf(yv,wA,aA[r]); aB[r]=fmaf(yv,wB,aB[r]); aC[r]=fmaf(yv,wC,aC[r]);
        }
    }
    float bA = bo[tid], bB = bo[tid+256], bC = (tid<128)? bo[tid+512] : 0.f;
    #pragma unroll
    for(int r=0;r<8;++r){
        int row = r0 + r, s = row >> 5, b = row & 31;
        int mm = tid & 127;
        out_mel[((size_t)b*TOUT_ + s*R_ + (tid>>7))*MEL_ + mm]     = aA[r] + bA;
        out_mel[((size_t)b*TOUT_ + s*R_ + 2 + (tid>>7))*MEL_ + mm] = aB[r] + bB;
        if(tid < 128)
            out_mel[((size_t)b*TOUT_ + s*R_ + 4)*MEL_ + tid]       = aC[r] + bC;
    }
}

// ---------------- K7: output_spec = mel @ Wspec + bspec ----------------
__global__ __launch_bounds__(256) void k_spec(const float* __restrict__ out_mel,
                                              const float* __restrict__ Wspec,
                                              const float* __restrict__ bspec,
                                              float* __restrict__ out_spec){
    __shared__ float m8[8][128];
    const int r0 = blockIdx.x * 8;
    const int tid = threadIdx.x;
    for(int i=tid; i<8*128; i+=256){ int r=i>>7, k=i&127; m8[r][k] = out_mel[(size_t)(r0+r)*128 + k]; }
    __syncthreads();
    float aA[8], aB[8], aC[8];
    #pragma unroll
    for(int r=0;r<8;++r){ aA[r]=0.f; aB[r]=0.f; aC[r]=0.f; }
    for(int k=0;k<128;++k){
        float wA = Wspec[(size_t)k*SPEC_ + tid];
        float wB = Wspec[(size_t)k*SPEC_ + 256 + tid];
        float wC = (tid == 0) ? Wspec[(size_t)k*SPEC_ + 512] : 0.f;
        #pragma unroll
        for(int r=0;r<8;++r){
            float mv = m8[r][k];
            aA[r]=fmaf(mv,wA,aA[r]); aB[r]=fmaf(mv,wB,aB[r]); aC[r]=fmaf(mv,wC,aC[r]);
        }
    }
    float bA = bspec[tid], bB = bspec[256+tid];
    #pragma unroll
    for(int r=0;r<8;++r){
        size_t row = (size_t)(r0 + r);
        out_spec[row*SPEC_ + tid]       = aA[r] + bA;
        out_spec[row*SPEC_ + 256 + tid] = aB[r] + bB;
        if(tid == 0) out_spec[row*SPEC_ + 512] = aC[r] + bspec[512];
    }
}

// ---------------- launcher ----------------
extern "C" void kernel_launch(void* const* d_in, const int* in_sizes, int n_in,
                              void* d_out, int out_size, void* d_ws, size_t ws_size,
                              hipStream_t stream) {
    const float* enc       = (const float*)d_in[0];
    const float* st        = (const float*)d_in[1];
    const float* mg        = (const float*)d_in[2];
    const int*   speaker   = (const int*)  d_in[3];
    const int*   inp_mask  = (const int*)  d_in[4];
    const float* spk_embed = (const float*)d_in[5];
    const float* Wp1=(const float*)d_in[6],  *bp1=(const float*)d_in[7];
    const float* Wp2=(const float*)d_in[8],  *bp2=(const float*)d_in[9];
    const float* Wg_att=(const float*)d_in[10], *bg_att=(const float*)d_in[11];
    const float* Wc_att=(const float*)d_in[12], *bc_att=(const float*)d_in[13];
    const float* Wk=(const float*)d_in[14], *Wq=(const float*)d_in[15], *v_att=(const float*)d_in[16];
    const float* Ws_pre=(const float*)d_in[17], *bs_pre=(const float*)d_in[18];
    const float* Wk_s=(const float*)d_in[19], *Wq_s=(const float*)d_in[20], *v_s=(const float*)d_in[21];
    const float* Wa=(const float*)d_in[22], *ba=(const float*)d_in[23];
    const float* Wg1=(const float*)d_in[24], *bg1=(const float*)d_in[25];
    const float* Wc1=(const float*)d_in[26], *bc1=(const float*)d_in[27];
    const float* Wg2=(const float*)d_in[28], *bg2=(const float*)d_in[29];
    const float* Wc2=(const float*)d_in[30], *bc2=(const float*)d_in[31];
    const float* Wo=(const float*)d_in[32], *bo=(const float*)d_in[33];
    const float* Wspec=(const float*)d_in[34], *bspec=(const float*)d_in[35];

    float* out       = (float*)d_out;
    float* out_mel   = out;             // 32*500*128
    float* out_spec  = out + 2048000;   // 32*500*513
    float* out_alpha = out + 10256000;  // 32*100*128

    char* ws = (char*)d_ws;
    float*    spk_sel = (float*)(ws + OFF_SPK2);
    float*    aco_spk = (float*)(ws + OFF_ACOSPK2);
    float*    ms_g    = (float*)(ws + OFF_MS2);
    float*    ks_g    = (float*)(ws + OFF_KS2);
    float*    preg    = (float*)(ws + OFF_PREG2);
    float*    prec    = (float*)(ws + OFF_PREC2);
    float*    y2g     = (float*)(ws + OFF_Y2G);
    ushort_t* keysp   = (ushort_t*)(ws + OFF_KEYSP);
    ushort_t* encp    = (ushort_t*)(ws + OFF_ENCP);

    hipMemsetAsync(d_ws, 0, ZB_END, stream);

    k_small<<<dim3(1), dim3(256), 0, stream>>>(st, Ws_pre, bs_pre, Wk_s, spk_embed,
                                               speaker, Wa, ba, spk_sel, aco_spk, ms_g, ks_g);
    k_keys   <<<dim3(256),  dim3(256), 0, stream>>>(enc, Wk, keysp);
    k_encperm<<<dim3(4096), dim3(256), 0, stream>>>(enc, encp);
    k_prenet <<<dim3(200),  dim3(256), 0, stream>>>(mg, spk_sel, Wp1, bp1, Wp2, bp2,
                                                    Wg_att, bg_att, Wc_att, bc_att, preg, prec);
    k_scan_coop<<<dim3(NWG_), dim3(512), 0, stream>>>(ws, Wg_att, Wc_att, Wq, Wq_s,
                                                      v_att, v_s, Wa, Wg1, Wc1, Wg2, Wc2,
                                                      bg1, bc1, bg2, bc2, inp_mask, out_alpha);
    k_omel <<<dim3(400),  dim3(256), 0, stream>>>(y2g, Wo, bo, out_mel);
    k_spec <<<dim3(2000), dim3(256), 0, stream>>>(out_mel, Wspec, bspec, out_spec);
}

// Round 3
// 5229.416 us; speedup vs baseline: 1.7753x; 1.7753x over previous
//
#include <hip/hip_runtime.h>

typedef unsigned short ushort_t;
typedef unsigned int   uint_t;
typedef __attribute__((ext_vector_type(8))) short  bf16x8;
typedef __attribute__((ext_vector_type(4))) float  f32x4;

#define B_      32
#define TIN_    128
#define TOUT_   500
#define R_      5
#define STEPS_  100
#define MEL_    128
#define SPEC_   513
#define NWG_    32

// ---------------- ws layout (bytes) ----------------
// zeroed each launch:
#define ZB_SLOTS   0          // 32*32 int (128B stride per WG)
#define ZB_AH      8192       // [32][256] bf16  h_att
#define ZB_ARH     24576      // [32][256] bf16  r*h_att
#define ZB_AHC     40960      // [32][512] bf16  [h_att | ctx]
#define ZB_AXH1    73728      // [32][512] bf16  [aco | h1]
#define ZB_AXRH1   106496     // [32][512] bf16  [aco | r*h1]
#define ZB_AY1H2   139264     // [32][512] bf16  [y1 | h2]
#define ZB_AY1RH2  172032     // [32][512] bf16  [y1 | r*h2]
#define ZB_QBUF    204800     // [32][256] bf16  qW
#define ZB_UBUF    221184     // [32][256] f32   u gates att
#define ZB_U1BUF   253952     // [32][256] f32
#define ZB_U2BUF   286720     // [32][256] f32
#define ZB_EBUF    319488     // [32][128] f32   attn scores
#define ZB_QSBUF   335872     // [32][2] f32 (padded)
#define ZB_HF      336896     // [32][256] f32 h_att master
#define ZB_H1F     369664
#define ZB_H2F     402432
#define ZB_END     435200
// written by prep kernels:
#define OFF_SPK2    501760    // 32*32 f32
#define OFF_ACOSPK2 505856    // 32*256 f32
#define OFF_MS2     538624    // 20 f32
#define OFF_KS2     539136    // 20 f32
#define OFF_PREG2   539648    // 100*32*512 f32
#define OFF_PREC2   7093248   // 100*32*256 f32
#define OFF_Y2G     10370048  // 100*32*256 f32
#define OFF_KEYSP   13646848  // [32 wg][32 b][4 t][256] bf16
#define OFF_ENCP    15744000  // [32 wg][32 b][128 t][8] bf16
// end 17,841,152

// ---------------- helpers ----------------
__device__ __forceinline__ float bf1(ushort_t u){ return __uint_as_float(((uint_t)u) << 16); }
__device__ __forceinline__ ushort_t f2bf(float f){
    uint_t b = __float_as_uint(f);
    uint_t r = (b + 0x7fffu + ((b >> 16) & 1u)) >> 16;
    return (ushort_t)r;
}
__device__ __forceinline__ float fexp2(float x){ return __builtin_amdgcn_exp2f(x); }
__device__ __forceinline__ float frcp(float x){ return __builtin_amdgcn_rcpf(x); }
__device__ __forceinline__ float sigm_f(float x){ return frcp(1.f + fexp2(-1.44269504f * x)); }
__device__ __forceinline__ float tanh_f(float x){
    float e = fexp2(2.88539008f * x);
    return 1.f - 2.f * frcp(e + 1.f);
}

// ---------------- K1: tiny constants ----------------
__global__ __launch_bounds__(256) void k_small(
    const float* __restrict__ st, const float* __restrict__ Ws_pre,
    const float* __restrict__ bs_pre, const float* __restrict__ Wk_s,
    const float* __restrict__ spk_embed, const int* __restrict__ speaker,
    const float* __restrict__ Wa, const float* __restrict__ ba,
    float* __restrict__ spk_sel, float* __restrict__ aco_spk,
    float* __restrict__ ms_g, float* __restrict__ ks_g)
{
    __shared__ float spk_l[B_*32];
    __shared__ float ms_l[20];
    const int tid = threadIdx.x;
    for(int i=tid; i<B_*32; i+=256){
        int b = i >> 5, j = i & 31;
        float v = spk_embed[speaker[b]*32 + j];
        spk_l[i] = v; spk_sel[i] = v;
    }
    if(tid < 20){
        int n = tid >> 1, j = tid & 1;
        float v = st[n*2]*Ws_pre[j] + st[n*2+1]*Ws_pre[2+j] + bs_pre[j];
        v = fmaxf(v, 0.f);
        ms_l[tid] = v; ms_g[tid] = v;
    }
    __syncthreads();
    if(tid < 20){
        int n = tid >> 1, j = tid & 1;
        ks_g[tid] = ms_l[n*2]*Wk_s[j] + ms_l[n*2+1]*Wk_s[2+j];
    }
    for(int i=tid; i<B_*256; i+=256){
        int b = i >> 8, n = i & 255;
        float acc = ba[n];
        #pragma unroll
        for(int k=0;k<32;++k) acc = fmaf(spk_l[b*32+k], Wa[(256+k)*256 + n], acc);
        aco_spk[i] = acc;
    }
}

// ---------------- K4: keys = enc @ Wk -> bf16 permuted for scan ----------------
__global__ __launch_bounds__(256) void k_keys(const float* __restrict__ enc,
                                              const float* __restrict__ Wk,
                                              ushort_t* __restrict__ keysp){
    __shared__ float x16[16][256];
    const int bid = blockIdx.x;      // 256 = 32 b * 8 tgroups
    const int b = bid >> 3, tg = bid & 7, t0 = tg*16;
    const int tid = threadIdx.x;
    for(int i=tid; i<16*256; i+=256){
        int r = i >> 8, k = i & 255;
        x16[r][k] = enc[((size_t)b*TIN_ + t0 + r)*256 + k];
    }
    __syncthreads();
    float acc[16];
    #pragma unroll
    for(int r=0;r<16;++r) acc[r] = 0.f;
    for(int k=0;k<256;++k){
        float w = Wk[k*256 + tid];
        #pragma unroll
        for(int r=0;r<16;++r) acc[r] = fmaf(x16[r][k], w, acc[r]);
    }
    #pragma unroll
    for(int r=0;r<16;++r){
        int t = t0 + r;
        keysp[((size_t)((t>>2)*32 + b)*4 + (t&3))*256 + tid] = f2bf(acc[r]);
    }
}

// ---------------- enc permute: enc_p[d>>3][b][t][d&7] ----------------
__global__ __launch_bounds__(256) void k_encperm(const float* __restrict__ enc,
                                                 ushort_t* __restrict__ encp){
    int o = blockIdx.x*256 + threadIdx.x;      // 4096 blocks -> 1,048,576
    int j = o & 7, t = (o>>3) & 127, b = (o>>10) & 31, wg = o >> 15;
    encp[o] = f2bf(enc[((size_t)b*TIN_ + t)*256 + wg*8 + j]);
}

// ---------------- K3: prenet + x-part of att-GRU for all steps ----------------
__global__ __launch_bounds__(256) void k_prenet(
    const float* __restrict__ mg, const float* __restrict__ spk_sel,
    const float* __restrict__ Wp1, const float* __restrict__ bp1,
    const float* __restrict__ Wp2, const float* __restrict__ bp2,
    const float* __restrict__ Wg_att, const float* __restrict__ bg_att,
    const float* __restrict__ Wc_att, const float* __restrict__ bc_att,
    float* __restrict__ preg, float* __restrict__ prec)
{
    __shared__ float fr[16][128];
    __shared__ float p1[16][256];
    __shared__ float p2[16][128];
    __shared__ float spk_l[16][32];
    const int r0 = blockIdx.x * 16;     // 200 blocks * 16 rows = 3200 (s*32+b)
    const int tid = threadIdx.x;
    for(int i=tid; i<16*128; i+=256){
        int r = i >> 7, mcol = i & 127;
        int row = r0 + r, s = row >> 5, b = row & 31;
        fr[r][mcol] = (s == 0) ? 0.f : mg[((size_t)b*TOUT_ + s*R_ - 1)*MEL_ + mcol];
    }
    for(int i=tid; i<16*32; i+=256){
        int r = i >> 5, j = i & 31;
        spk_l[r][j] = spk_sel[((r0 + r) & 31)*32 + j];
    }
    __syncthreads();
    {
        float acc[16];
        #pragma unroll
        for(int r=0;r<16;++r) acc[r]=0.f;
        for(int k=0;k<128;++k){
            float w = Wp1[k*256 + tid];
            #pragma unroll
            for(int r=0;r<16;++r) acc[r] = fmaf(fr[r][k], w, acc[r]);
        }
        float bb = bp1[tid];
        #pragma unroll
        for(int r=0;r<16;++r) p1[r][tid] = fmaxf(acc[r] + bb, 0.f);
    }
    __syncthreads();
    if(tid < 128){
        float acc[16];
        #pragma unroll
        for(int r=0;r<16;++r) acc[r]=0.f;
        for(int k=0;k<256;++k){
            float w = Wp2[k*128 + tid];
            #pragma unroll
            for(int r=0;r<16;++r) acc[r] = fmaf(p1[r][k], w, acc[r]);
        }
        float bb = bp2[tid];
        #pragma unroll
        for(int r=0;r<16;++r) p2[r][tid] = fmaxf(acc[r] + bb, 0.f);
    }
    __syncthreads();
    {
        float aA[16], aB[16];
        #pragma unroll
        for(int r=0;r<16;++r){ aA[r]=0.f; aB[r]=0.f; }
        for(int k=0;k<128;++k){
            float wA = Wg_att[k*512 + tid], wB = Wg_att[k*512 + tid + 256];
            #pragma unroll
            for(int r=0;r<16;++r){ float pv = p2[r][k]; aA[r]=fmaf(pv,wA,aA[r]); aB[r]=fmaf(pv,wB,aB[r]); }
        }
        for(int k=0;k<32;++k){
            float wA = Wg_att[(128+k)*512 + tid], wB = Wg_att[(128+k)*512 + tid + 256];
            #pragma unroll
            for(int r=0;r<16;++r){ float sv = spk_l[r][k]; aA[r]=fmaf(sv,wA,aA[r]); aB[r]=fmaf(sv,wB,aB[r]); }
        }
        float bA = bg_att[tid], bB = bg_att[tid + 256];
        #pragma unroll
        for(int r=0;r<16;++r){
            preg[(size_t)(r0+r)*512 + tid]       = aA[r] + bA;
            preg[(size_t)(r0+r)*512 + tid + 256] = aB[r] + bB;
        }
    }
    {
        float acc[16];
        #pragma unroll
        for(int r=0;r<16;++r) acc[r]=0.f;
        for(int k=0;k<128;++k){
            float w = Wc_att[k*256 + tid];
            #pragma unroll
            for(int r=0;r<16;++r) acc[r] = fmaf(p2[r][k], w, acc[r]);
        }
        for(int k=0;k<32;++k){
            float w = Wc_att[(128+k)*256 + tid];
            #pragma unroll
            for(int r=0;r<16;++r) acc[r] = fmaf(spk_l[r][k], w, acc[r]);
        }
        float bb = bc_att[tid];
        #pragma unroll
        for(int r=0;r<16;++r) prec[(size_t)(r0+r)*256 + tid] = acc[r] + bb;
    }
}

// ---------------- cooperative scan helpers ----------------
// Cheap agent barrier: release flag (one wbl2), RELAXED polls (no per-poll L2
// invalidate!), then ONE acquire fence (one buffer_inv) after flags observed.
__device__ __forceinline__ void gridbar(int* slots, int p, int seq, int tid){
    __syncthreads();
    if(tid == 0)
        __hip_atomic_store(&slots[p*32], seq, __ATOMIC_RELEASE, __HIP_MEMORY_SCOPE_AGENT);
    if(tid < NWG_){
        while(__hip_atomic_load(&slots[tid*32], __ATOMIC_RELAXED, __HIP_MEMORY_SCOPE_AGENT) < seq)
            __builtin_amdgcn_s_sleep(2);
        __builtin_amdgcn_fence(__ATOMIC_ACQUIRE, "agent");
    }
    __syncthreads();
}

// load weight col-slice (bf16, col-major [16][Ktot], XOR-swizzled) into LDS
__device__ __forceinline__ void loadW(const float* W, int ldw, int rowbase, int nk, int kbase,
                                      int Ktot, int col0, int ncols, ushort_t* lds, int tid){
    for(int e = tid; e < 16*nk; e += 512){
        int col = e & 15, k = e >> 4;
        ushort_t v = 0;
        if(col < ncols) v = f2bf(W[(size_t)(rowbase + k)*ldw + col0 + col]);
        lds[(col*Ktot + kbase + k) ^ ((col & 7) << 3)] = v;
    }
}

// GEMM: C[32][Ns] += A[32][K] (global bf16) * W (LDS [16][K] colmajor swz)
template<int K>
__device__ __forceinline__ f32x4 do_gemm(const ushort_t* Ab, const ushort_t* Wl, float* red,
                                         int m, int kq, int lane){
    f32x4 acc = {0.f,0.f,0.f,0.f};
    const int row = m*16 + (lane & 15);
    const int col = lane & 15;
    const int ko  = (lane >> 4) * 8;
    #pragma unroll
    for(int t = 0; t < K/128; ++t){
        const int k0 = kq*(K/4) + t*32 + ko;
        bf16x8 a = *reinterpret_cast<const bf16x8*>(Ab + row*K + k0);
        bf16x8 b = *reinterpret_cast<const bf16x8*>(Wl + ((col*K + k0) ^ ((col & 7) << 3)));
        acc = __builtin_amdgcn_mfma_f32_16x16x32_bf16(a, b, acc, 0, 0, 0);
    }
    if(kq > 0) *reinterpret_cast<f32x4*>(red + ((kq-1)*2 + m)*256 + lane*4) = acc;
    __syncthreads();
    if(kq == 0){
        #pragma unroll
        for(int j = 0; j < 3; ++j)
            acc += *reinterpret_cast<const f32x4*>(red + (j*2 + m)*256 + lane*4);
    }
    return acc;
}

// ---------------- K5: the cooperative scan ----------------
__global__ __launch_bounds__(512) void k_scan_coop(
    char* ws,
    const float* __restrict__ Wg_att, const float* __restrict__ Wc_att,
    const float* __restrict__ Wq, const float* __restrict__ Wq_s,
    const float* __restrict__ v_att, const float* __restrict__ v_s,
    const float* __restrict__ Wa,
    const float* __restrict__ Wg1, const float* __restrict__ Wc1,
    const float* __restrict__ Wg2, const float* __restrict__ Wc2,
    const float* __restrict__ bg1, const float* __restrict__ bc1,
    const float* __restrict__ bg2, const float* __restrict__ bc2,
    const int* __restrict__ inp_mask, float* __restrict__ out_alpha)
{
    const int p = blockIdx.x, tid = threadIdx.x;
    const int lane = tid & 63, wv = tid >> 6;
    const int m = wv & 1, kq = wv >> 1;

    int* slots      = (int*)(ws + ZB_SLOTS);
    ushort_t* A_h    = (ushort_t*)(ws + ZB_AH);
    ushort_t* A_rh   = (ushort_t*)(ws + ZB_ARH);
    ushort_t* A_hc   = (ushort_t*)(ws + ZB_AHC);
    ushort_t* A_xh1  = (ushort_t*)(ws + ZB_AXH1);
    ushort_t* A_xrh1 = (ushort_t*)(ws + ZB_AXRH1);
    ushort_t* A_y1h2 = (ushort_t*)(ws + ZB_AY1H2);
    ushort_t* A_y1rh2= (ushort_t*)(ws + ZB_AY1RH2);
    ushort_t* Qbuf   = (ushort_t*)(ws + ZB_QBUF);
    float* ubuf  = (float*)(ws + ZB_UBUF);
    float* u1buf = (float*)(ws + ZB_U1BUF);
    float* u2buf = (float*)(ws + ZB_U2BUF);
    float* ebuf  = (float*)(ws + ZB_EBUF);
    float* qsbuf = (float*)(ws + ZB_QSBUF);
    float* hf    = (float*)(ws + ZB_HF);
    float* h1f   = (float*)(ws + ZB_H1F);
    float* h2f   = (float*)(ws + ZB_H2F);
    const float* acospk = (const float*)(ws + OFF_ACOSPK2);
    const float* msg    = (const float*)(ws + OFF_MS2);
    const float* ksg    = (const float*)(ws + OFF_KS2);
    const float* preg   = (const float*)(ws + OFF_PREG2);
    const float* prec   = (const float*)(ws + OFF_PREC2);
    float* y2g          = (float*)(ws + OFF_Y2G);
    const ushort_t* keysp = (const ushort_t*)(ws + OFF_KEYSP);
    const ushort_t* encp  = (const ushort_t*)(ws + OFF_ENCP);

    // LDS: resident weight slices (col-major [16][K], bf16, swizzled)
    __shared__ ushort_t wA[16*256], wB[16*256], wC[16*256];
    __shared__ ushort_t wG[16*512], wH[16*512], wI[16*512], wJ[16*512], wK[16*512];
    __shared__ __align__(16) char uni[16384];     // union: red (6KB f32) | qlds (16KB bf16)
    float* red = (float*)uni;
    ushort_t* qlds = (ushort_t*)uni;
    __shared__ float vatt_l[256];
    __shared__ float msks[48];
    __shared__ float ctxs_l[64];
    // WG-private per-step state (was global; avoid post-inv LLC refetch)
    __shared__ float acosl[256];                 // acospk col-slice [32][8]
    __shared__ float acofl[256], y1fl[256];      // aco, y1 col-slices [32][8]
    __shared__ float bg1s[16], bc1s[8], bg2s[16], bc2s[8], wasl[16];
    __shared__ int   maskl[32];

    loadW(Wg_att, 512, 160, 256, 0, 256, p*16, 16, wA, tid);
    loadW(Wc_att, 256, 160, 256, 0, 256, p*8,  8,  wB, tid);
    loadW(Wq,     256, 0,   256, 0, 256, p*8,  8,  wC, tid);
    loadW(Wa,     256, 0,   256, 0,   512, p*8, 8, wG, tid);   // rows 0..255  (h)
    loadW(Wa,     256, 288, 256, 256, 512, p*8, 8, wG, tid);   // rows 288..543 (ctx)
    loadW(Wg1,    512, 0,   512, 0, 512, p*16, 16, wH, tid);
    loadW(Wc1,    256, 0,   512, 0, 512, p*8,  8,  wI, tid);
    loadW(Wg2,    512, 0,   512, 0, 512, p*16, 16, wJ, tid);
    loadW(Wc2,    256, 0,   512, 0, 512, p*8,  8,  wK, tid);
    if(tid < 256) vatt_l[tid] = v_att[tid];
    if(tid < 256) acosl[tid] = acospk[(tid>>3)*256 + p*8 + (tid&7)];
    if(tid < 20) msks[tid] = msg[tid];
    if(tid >= 20 && tid < 40) msks[tid] = ksg[tid-20];
    if(tid == 40) msks[40] = v_s[0];
    if(tid == 41) msks[41] = v_s[1];
    if(tid < 16){ bg1s[tid] = bg1[p*16+tid]; bg2s[tid] = bg2[p*16+tid]; }
    if(tid < 8){ bc1s[tid] = bc1[p*8+tid]; bc2s[tid] = bc2[p*8+tid]; }
    if(tid < 16) wasl[tid] = Wa[(size_t)(544 + (tid & 1))*256 + p*8 + (tid >> 1)];
    if(tid < 32) maskl[tid] = inp_mask[tid];
    __syncthreads();

    int seq = 0;
    for(int s = 0; s < STEPS_; ++s){
        const int sb = s*32;
        // ---- A: att-GRU gates ----
        __syncthreads();   // guard red WAR vs stage K of prev step
        f32x4 acc = do_gemm<256>(A_h, wA, red, m, kq, lane);
        if(kq == 0){
            int col = lane & 15, gcol = p*16 + col;
            #pragma unroll
            for(int r=0;r<4;++r){
                int b = m*16 + ((lane>>4)<<2) + r;
                float g = sigm_f(acc[r] + preg[(size_t)(sb + b)*512 + gcol]);
                if(p < 16) A_rh[b*256 + gcol] = f2bf(g * hf[b*256 + gcol]);
                else       ubuf[b*256 + gcol - 256] = g;
            }
        }
        gridbar(slots, p, ++seq, tid);
        // ---- B: att-GRU candidate + h update ----
        acc = do_gemm<256>(A_rh, wB, red, m, kq, lane);
        if(kq == 0 && (lane & 15) < 8){
            int gcol = p*8 + (lane & 15);
            #pragma unroll
            for(int r=0;r<4;++r){
                int b = m*16 + ((lane>>4)<<2) + r;
                float cc = tanh_f(acc[r] + prec[(size_t)(sb + b)*256 + gcol]);
                float u  = ubuf[b*256 + gcol];
                float hn = u*hf[b*256 + gcol] + (1.f - u)*cc;
                hf[b*256 + gcol] = hn;
                ushort_t hb = f2bf(hn);
                A_h[b*256 + gcol] = hb;
                A_hc[b*512 + gcol] = hb;
            }
        }
        gridbar(slots, p, ++seq, tid);
        // ---- C: qW = h @ Wq (+ style query on p0) ----
        acc = do_gemm<256>(A_h, wC, red, m, kq, lane);
        if(kq == 0 && (lane & 15) < 8){
            int gcol = p*8 + (lane & 15);
            #pragma unroll
            for(int r=0;r<4;++r){
                int b = m*16 + ((lane>>4)<<2) + r;
                Qbuf[b*256 + gcol] = f2bf(acc[r]);
            }
        }
        if(p == 0){
            int b = tid >> 4, i = tid & 15;
            float q0 = 0.f, q1 = 0.f;
            #pragma unroll
            for(int kk=0; kk<16; ++kk){
                int k = i*16 + kk;
                float hv = hf[b*256 + k];
                q0 = fmaf(hv, Wq_s[k*2],   q0);
                q1 = fmaf(hv, Wq_s[k*2+1], q1);
            }
            #pragma unroll
            for(int d=1; d<16; d<<=1){ q0 += __shfl_xor(q0,d,64); q1 += __shfl_xor(q1,d,64); }
            if(i == 0){ qsbuf[b*2] = q0; qsbuf[b*2+1] = q1; }
        }
        gridbar(slots, p, ++seq, tid);
        // ---- D: attention scores (t-slice of 4 per WG) ----
        ((bf16x8*)qlds)[tid]       = ((const bf16x8*)Qbuf)[tid];
        ((bf16x8*)qlds)[tid + 512] = ((const bf16x8*)Qbuf)[tid + 512];
        __syncthreads();
        {
            int b = tid >> 4, tl = (tid >> 2) & 3, q = tid & 3;
            int tg = p*4 + tl;
            const ushort_t* kp = keysp + (((size_t)p*32 + b)*4 + tl)*256 + q*64;
            const ushort_t* qp = qlds + b*256 + q*64;
            float e = 0.f;
            #pragma unroll
            for(int i=0;i<8;++i){
                bf16x8 kv = *(const bf16x8*)(kp + i*8);
                bf16x8 qv = *(const bf16x8*)(qp + i*8);
                #pragma unroll
                for(int j=0;j<8;++j){
                    int a = q*64 + i*8 + j;
                    e = fmaf(vatt_l[a], tanh_f(bf1((ushort_t)kv[j]) + bf1((ushort_t)qv[j])), e);
                }
            }
            e += __shfl_xor(e, 1, 64); e += __shfl_xor(e, 2, 64);
            if(q == 0) ebuf[b*128 + tg] = (tg < maskl[b]) ? e : -1e9f;
        }
        gridbar(slots, p, ++seq, tid);
        // ---- E: redundant softmax + context col-slice + style ctx ----
        {
            int b = tid >> 4, i = tid & 15;
            f32x4 e0 = *(const f32x4*)(ebuf + b*128 + i*8);
            f32x4 e1 = *(const f32x4*)(ebuf + b*128 + i*8 + 4);
            float mx = fmaxf(fmaxf(fmaxf(e0[0],e0[1]),fmaxf(e0[2],e0[3])),
                             fmaxf(fmaxf(e1[0],e1[1]),fmaxf(e1[2],e1[3])));
            #pragma unroll
            for(int d=1; d<16; d<<=1) mx = fmaxf(mx, __shfl_xor(mx,d,64));
            float a8[8]; float sum = 0.f;
            #pragma unroll
            for(int j=0;j<8;++j){
                float ev = (j<4)? e0[j] : e1[j-4];
                a8[j] = fexp2((ev - mx)*1.44269504f);
                sum += a8[j];
            }
            #pragma unroll
            for(int d=1; d<16; d<<=1) sum += __shfl_xor(sum,d,64);
            float inv = frcp(sum);
            #pragma unroll
            for(int j=0;j<8;++j) a8[j] *= inv;
            if(p == 1){
                float* oa = out_alpha + ((size_t)b*STEPS_ + s)*TIN_ + i*8;
                #pragma unroll
                for(int j=0;j<8;++j) oa[j] = a8[j];
            }
            float cj[8] = {0,0,0,0,0,0,0,0};
            const ushort_t* ep = encp + (((size_t)p*32 + b)*128 + i*8)*8;
            #pragma unroll
            for(int t2=0;t2<8;++t2){
                bf16x8 ev = *(const bf16x8*)(ep + t2*8);
                #pragma unroll
                for(int j=0;j<8;++j) cj[j] = fmaf(a8[t2], bf1((ushort_t)ev[j]), cj[j]);
            }
            #pragma unroll
            for(int d=1; d<16; d<<=1){
                #pragma unroll
                for(int j=0;j<8;++j) cj[j] += __shfl_xor(cj[j],d,64);
            }
            if(i == 0){
                bf16x8 pk;
                #pragma unroll
                for(int j=0;j<8;++j) pk[j] = (short)f2bf(cj[j]);
                *(bf16x8*)(A_hc + b*512 + 256 + p*8) = pk;
            }
        }
        if(tid < 32){
            int b = tid;
            float q0 = qsbuf[b*2], q1 = qsbuf[b*2+1];
            float es[10]; float mx = -1e30f;
            #pragma unroll
            for(int n=0;n<10;++n){
                float t = msks[40]*tanh_f(msks[20+n*2] + q0) + msks[41]*tanh_f(msks[20+n*2+1] + q1);
                es[n] = t; mx = fmaxf(mx, t);
            }
            float sum = 0.f;
            #pragma unroll
            for(int n=0;n<10;++n){ float pe = fexp2((es[n]-mx)*1.44269504f); es[n]=pe; sum += pe; }
            float inv = frcp(sum); float c0=0.f, c1=0.f;
            #pragma unroll
            for(int n=0;n<10;++n){ float al = es[n]*inv; c0 = fmaf(al, msks[n*2], c0); c1 = fmaf(al, msks[n*2+1], c1); }
            ctxs_l[b*2] = c0; ctxs_l[b*2+1] = c1;
        }
        gridbar(slots, p, ++seq, tid);
        // ---- G: aco = [h|ctx]@Wa + acospk + ctx_s@Wa_s ----
        acc = do_gemm<512>(A_hc, wG, red, m, kq, lane);
        if(kq == 0 && (lane & 15) < 8){
            int col = lane & 15, gcol = p*8 + col;
            #pragma unroll
            for(int r=0;r<4;++r){
                int b = m*16 + ((lane>>4)<<2) + r;
                float v = acc[r] + acosl[b*8 + col]
                        + ctxs_l[b*2]   * wasl[col*2]
                        + ctxs_l[b*2+1] * wasl[col*2+1];
                acofl[b*8 + col] = v;
                ushort_t vb = f2bf(v);
                A_xh1[b*512 + gcol] = vb;
                A_xrh1[b*512 + gcol] = vb;
            }
        }
        gridbar(slots, p, ++seq, tid);
        // ---- H: GRU1 gates ----
        acc = do_gemm<512>(A_xh1, wH, red, m, kq, lane);
        if(kq == 0){
            int col = lane & 15, gcol = p*16 + col;
            #pragma unroll
            for(int r=0;r<4;++r){
                int b = m*16 + ((lane>>4)<<2) + r;
                float g = sigm_f(acc[r] + bg1s[col]);
                if(p < 16) A_xrh1[b*512 + 256 + gcol] = f2bf(g * h1f[b*256 + gcol]);
                else       u1buf[b*256 + gcol - 256] = g;
            }
        }
        gridbar(slots, p, ++seq, tid);
        // ---- I: GRU1 candidate + y1 ----
        acc = do_gemm<512>(A_xrh1, wI, red, m, kq, lane);
        if(kq == 0 && (lane & 15) < 8){
            int col = lane & 15, gcol = p*8 + col;
            #pragma unroll
            for(int r=0;r<4;++r){
                int b = m*16 + ((lane>>4)<<2) + r;
                float cc = tanh_f(acc[r] + bc1s[col]);
                float u  = u1buf[b*256 + gcol];
                float hn = u*h1f[b*256 + gcol] + (1.f - u)*cc;
                h1f[b*256 + gcol] = hn;
                A_xh1[b*512 + 256 + gcol] = f2bf(hn);
                float y1 = hn + acofl[b*8 + col];
                y1fl[b*8 + col] = y1;
                ushort_t yb = f2bf(y1);
                A_y1h2[b*512 + gcol] = yb;
                A_y1rh2[b*512 + gcol] = yb;
            }
        }
        gridbar(slots, p, ++seq, tid);
        // ---- J: GRU2 gates ----
        acc = do_gemm<512>(A_y1h2, wJ, red, m, kq, lane);
        if(kq == 0){
            int col = lane & 15, gcol = p*16 + col;
            #pragma unroll
            for(int r=0;r<4;++r){
                int b = m*16 + ((lane>>4)<<2) + r;
                float g = sigm_f(acc[r] + bg2s[col]);
                if(p < 16) A_y1rh2[b*512 + 256 + gcol] = f2bf(g * h2f[b*256 + gcol]);
                else       u2buf[b*256 + gcol - 256] = g;
            }
        }
        gridbar(slots, p, ++seq, tid);
        // ---- K: GRU2 candidate + y2 (no barrier; next stage A doesn't conflict) ----
        acc = do_gemm<512>(A_y1rh2, wK, red, m, kq, lane);
        if(kq == 0 && (lane & 15) < 8){
            int col = lane & 15, gcol = p*8 + col;
            #pragma unroll
            for(int r=0;r<4;++r){
                int b = m*16 + ((lane>>4)<<2) + r;
                float cc = tanh_f(acc[r] + bc2s[col]);
                float u  = u2buf[b*256 + gcol];
                float hn = u*h2f[b*256 + gcol] + (1.f - u)*cc;
                h2f[b*256 + gcol] = hn;
                A_y1h2[b*512 + 256 + gcol] = f2bf(hn);
                y2g[((size_t)sb + b)*256 + gcol] = hn + y1fl[b*8 + col];
            }
        }
    }
}

// ---------------- K6: output_mel = y2 @ Wo + bo ----------------
__global__ __launch_bounds__(256) void k_omel(const float* __restrict__ y2g,
                                              const float* __restrict__ Wo,
                                              const float* __restrict__ bo,
                                              float* __restrict__ out_mel){
    __shared__ float y8[8][256];
    const int r0 = blockIdx.x * 8;
    const int tid = threadIdx.x;
    for(int i=tid; i<8*256; i+=256){ int r=i>>8, k=i&255; y8[r][k] = y2g[(size_t)(r0+r)*256 + k]; }
    __syncthreads();
    float aA[8], aB[8], aC[8];
    #pragma unroll
    for(int r=0;r<8;++r){ aA[r]=0.f; aB[r]=0.f; aC[r]=0.f; }
    for(int k=0;k<256;++k){
        float wA = Wo[(size_t)k*640 + tid];
        float wB = Wo[(size_t)k*640 + tid + 256];
        float wC = (tid < 128) ? Wo[(size_t)k*640 + tid + 512] : 0.f;
        #pragma unroll
        for(int r=0;r<8;++r){
            float yv = y8[r][k];
            aA[r]=fmaf(yv,wA,aA[r]); aB[r]=fmaf(yv,wB,aB[r]); aC[r]=fmaf(yv,wC,aC[r]);
        }
    }
    float bA = bo[tid], bB = bo[tid+256], bC = (tid<128)? bo[tid+512] : 0.f;
    #pragma unroll
    for(int r=0;r<8;++r){
        int row = r0 + r, s = row >> 5, b = row & 31;
        int mm = tid & 127;
        out_mel[((size_t)b*TOUT_ + s*R_ + (tid>>7))*MEL_ + mm]     = aA[r] + bA;
        out_mel[((size_t)b*TOUT_ + s*R_ + 2 + (tid>>7))*MEL_ + mm] = aB[r] + bB;
        if(tid < 128)
            out_mel[((size_t)b*TOUT_ + s*R_ + 4)*MEL_ + tid]       = aC[r] + bC;
    }
}

// ---------------- K7: output_spec = mel @ Wspec + bspec ----------------
__global__ __launch_bounds__(256) void k_spec(const float* __restrict__ out_mel,
                                              const float* __restrict__ Wspec,
                                              const float* __restrict__ bspec,
                                              float* __restrict__ out_spec){
    __shared__ float m8[8][128];
    const int r0 = blockIdx.x * 8;
    const int tid = threadIdx.x;
    for(int i=tid; i<8*128; i+=256){ int r=i>>7, k=i&127; m8[r][k] = out_mel[(size_t)(r0+r)*128 + k]; }
    __syncthreads();
    float aA[8], aB[8], aC[8];
    #pragma unroll
    for(int r=0;r<8;++r){ aA[r]=0.f; aB[r]=0.f; aC[r]=0.f; }
    for(int k=0;k<128;++k){
        float wA = Wspec[(size_t)k*SPEC_ + tid];
        float wB = Wspec[(size_t)k*SPEC_ + 256 + tid];
        float wC = (tid == 0) ? Wspec[(size_t)k*SPEC_ + 512] : 0.f;
        #pragma unroll
        for(int r=0;r<8;++r){
            float mv = m8[r][k];
            aA[r]=fmaf(mv,wA,aA[r]); aB[r]=fmaf(mv,wB,aB[r]); aC[r]=fmaf(mv,wC,aC[r]);
        }
    }
    float bA = bspec[tid], bB = bspec[256+tid];
    #pragma unroll
    for(int r=0;r<8;++r){
        size_t row = (size_t)(r0 + r);
        out_spec[row*SPEC_ + tid]       = aA[r] + bA;
        out_spec[row*SPEC_ + 256 + tid] = aB[r] + bB;
        if(tid == 0) out_spec[row*SPEC_ + 512] = aC[r] + bspec[512];
    }
}

// ---------------- launcher ----------------
extern "C" void kernel_launch(void* const* d_in, const int* in_sizes, int n_in,
                              void* d_out, int out_size, void* d_ws, size_t ws_size,
                              hipStream_t stream) {
    const float* enc       = (const float*)d_in[0];
    const float* st        = (const float*)d_in[1];
    const float* mg        = (const float*)d_in[2];
    const int*   speaker   = (const int*)  d_in[3];
    const int*   inp_mask  = (const int*)  d_in[4];
    const float* spk_embed = (const float*)d_in[5];
    const float* Wp1=(const float*)d_in[6],  *bp1=(const float*)d_in[7];
    const float* Wp2=(const float*)d_in[8],  *bp2=(const float*)d_in[9];
    const float* Wg_att=(const float*)d_in[10], *bg_att=(const float*)d_in[11];
    const float* Wc_att=(const float*)d_in[12], *bc_att=(const float*)d_in[13];
    const float* Wk=(const float*)d_in[14], *Wq=(const float*)d_in[15], *v_att=(const float*)d_in[16];
    const float* Ws_pre=(const float*)d_in[17], *bs_pre=(const float*)d_in[18];
    const float* Wk_s=(const float*)d_in[19], *Wq_s=(const float*)d_in[20], *v_s=(const float*)d_in[21];
    const float* Wa=(const float*)d_in[22], *ba=(const float*)d_in[23];
    const float* Wg1=(const float*)d_in[24], *bg1=(const float*)d_in[25];
    const float* Wc1=(const float*)d_in[26], *bc1=(const float*)d_in[27];
    const float* Wg2=(const float*)d_in[28], *bg2=(const float*)d_in[29];
    const float* Wc2=(const float*)d_in[30], *bc2=(const float*)d_in[31];
    const float* Wo=(const float*)d_in[32], *bo=(const float*)d_in[33];
    const float* Wspec=(const float*)d_in[34], *bspec=(const float*)d_in[35];

    float* out       = (float*)d_out;
    float* out_mel   = out;             // 32*500*128
    float* out_spec  = out + 2048000;   // 32*500*513
    float* out_alpha = out + 10256000;  // 32*100*128

    char* ws = (char*)d_ws;
    float*    spk_sel = (float*)(ws + OFF_SPK2);
    float*    aco_spk = (float*)(ws + OFF_ACOSPK2);
    float*    ms_g    = (float*)(ws + OFF_MS2);
    float*    ks_g    = (float*)(ws + OFF_KS2);
    float*    preg    = (float*)(ws + OFF_PREG2);
    float*    prec    = (float*)(ws + OFF_PREC2);
    float*    y2g     = (float*)(ws + OFF_Y2G);
    ushort_t* keysp   = (ushort_t*)(ws + OFF_KEYSP);
    ushort_t* encp    = (ushort_t*)(ws + OFF_ENCP);

    hipMemsetAsync(d_ws, 0, ZB_END, stream);

    k_small<<<dim3(1), dim3(256), 0, stream>>>(st, Ws_pre, bs_pre, Wk_s, spk_embed,
                                               speaker, Wa, ba, spk_sel, aco_spk, ms_g, ks_g);
    k_keys   <<<dim3(256),  dim3(256), 0, stream>>>(enc, Wk, keysp);
    k_encperm<<<dim3(4096), dim3(256), 0, stream>>>(enc, encp);
    k_prenet <<<dim3(200),  dim3(256), 0, stream>>>(mg, spk_sel, Wp1, bp1, Wp2, bp2,
                                                    Wg_att, bg_att, Wc_att, bc_att, preg, prec);
    k_scan_coop<<<dim3(NWG_), dim3(512), 0, stream>>>(ws, Wg_att, Wc_att, Wq, Wq_s,
                                                      v_att, v_s, Wa, Wg1, Wc1, Wg2, Wc2,
                                                      bg1, bc1, bg2, bc2, inp_mask, out_alpha);
    k_omel <<<dim3(400),  dim3(256), 0, stream>>>(y2g, Wo, bo, out_mel);
    k_spec <<<dim3(2000), dim3(256), 0, stream>>>(out_mel, Wspec, bspec, out_spec);
}

// Round 5
// 3909.470 us; speedup vs baseline: 2.3747x; 1.3376x over previous
//
#include <hip/hip_runtime.h>

typedef unsigned short ushort_t;
typedef unsigned int   uint_t;
typedef unsigned long long u64;
typedef __attribute__((ext_vector_type(8))) short  bf16x8;
typedef __attribute__((ext_vector_type(4))) float  f32x4;

#define B_      32
#define TIN_    128
#define TOUT_   500
#define R_      5
#define STEPS_  100
#define MEL_    128
#define SPEC_   513
#define NWG_    32

// ---------------- ws layout (bytes) ----------------
// zeroed each launch:
#define ZB_SLOTS   0          // 32*32 int (128B stride per WG)
#define ZB_AH      8192       // [32][256] bf16  h_att
#define ZB_ARH     24576      // [32][256] bf16  r*h_att
#define ZB_AHC     40960      // [32][512] bf16  [h_att | ctx]
#define ZB_AXH1    73728      // [32][512] bf16  [aco | h1]
#define ZB_AXRH1   106496     // [32][512] bf16  [aco | r*h1]
#define ZB_AY1H2   139264     // [32][512] bf16  [y1 | h2]
#define ZB_AY1RH2  172032     // [32][512] bf16  [y1 | r*h2]
#define ZB_QBUF    204800     // [32][256] bf16  qW
#define ZB_UBUF    221184     // [32][256] f32   u gates att
#define ZB_U1BUF   253952     // [32][256] f32
#define ZB_U2BUF   286720     // [32][256] f32
#define ZB_EBUF    319488     // [32][128] f32   attn scores
#define ZB_QSBUF   335872     // [32][2] f32 (padded)
#define ZB_END     435200
// written by prep kernels:
#define OFF_SPK2    501760    // 32*32 f32
#define OFF_ACOSPK2 505856    // 32*256 f32
#define OFF_MS2     538624    // 20 f32
#define OFF_KS2     539136    // 20 f32
#define OFF_PREG2   539648    // 100*32*512 f32
#define OFF_PREC2   7093248   // 100*32*256 f32
#define OFF_Y2G     10370048  // 100*32*256 f32
#define OFF_KEYSP   13646848  // [32 wg][32 b][4 t][256] bf16
#define OFF_ENCP    15744000  // [32 wg][32 b][128 t][8] bf16
// end 17,841,152

// ---------------- helpers ----------------
__device__ __forceinline__ float bf1(ushort_t u){ return __uint_as_float(((uint_t)u) << 16); }
__device__ __forceinline__ ushort_t f2bf(float f){
    uint_t b = __float_as_uint(f);
    uint_t r = (b + 0x7fffu + ((b >> 16) & 1u)) >> 16;
    return (ushort_t)r;
}
__device__ __forceinline__ float fexp2(float x){ return __builtin_amdgcn_exp2f(x); }
__device__ __forceinline__ float frcp(float x){ return __builtin_amdgcn_rcpf(x); }
__device__ __forceinline__ float sigm_f(float x){ return frcp(1.f + fexp2(-1.44269504f * x)); }
__device__ __forceinline__ float tanh_f(float x){
    float e = fexp2(2.88539008f * x);
    return 1.f - 2.f * frcp(e + 1.f);
}
// LLC-coherent (cache-bypassing) relaxed agent atomics — per-instruction
// coherence, NO cache-wide fences anywhere in the scan loop.
__device__ __forceinline__ u64 ld8(const void* p){
    return __hip_atomic_load((const u64*)p, __ATOMIC_RELAXED, __HIP_MEMORY_SCOPE_AGENT);
}
__device__ __forceinline__ void st8(void* p, u64 v){
    __hip_atomic_store((u64*)p, v, __ATOMIC_RELAXED, __HIP_MEMORY_SCOPE_AGENT);
}
__device__ __forceinline__ float ld4f(const void* p){
    uint_t u = __hip_atomic_load((const uint_t*)p, __ATOMIC_RELAXED, __HIP_MEMORY_SCOPE_AGENT);
    return __uint_as_float(u);
}
__device__ __forceinline__ void st4f(void* p, float v){
    __hip_atomic_store((uint_t*)p, __float_as_uint(v), __ATOMIC_RELAXED, __HIP_MEMORY_SCOPE_AGENT);
}
__device__ __forceinline__ float u64lo(u64 v){ return __uint_as_float((uint_t)v); }
__device__ __forceinline__ float u64hi(u64 v){ return __uint_as_float((uint_t)(v >> 32)); }
// Same-type LDS reads packed in registers (NO u64 punning of ushort/float LDS:
// that was r4's UB — TBAA let the compiler reorder ds_writes past the reads).
__device__ __forceinline__ u64 pack4(const ushort_t* q){
    return (u64)q[0] | ((u64)q[1] << 16) | ((u64)q[2] << 32) | ((u64)q[3] << 48);
}
__device__ __forceinline__ u64 pack2f(const float* f){
    return (u64)__float_as_uint(f[0]) | ((u64)__float_as_uint(f[1]) << 32);
}
#define CBAR() asm volatile("" ::: "memory")   // compiler-order LDS write->read (same wave)

// ---------------- K1: tiny constants ----------------
__global__ __launch_bounds__(256) void k_small(
    const float* __restrict__ st, const float* __restrict__ Ws_pre,
    const float* __restrict__ bs_pre, const float* __restrict__ Wk_s,
    const float* __restrict__ spk_embed, const int* __restrict__ speaker,
    const float* __restrict__ Wa, const float* __restrict__ ba,
    float* __restrict__ spk_sel, float* __restrict__ aco_spk,
    float* __restrict__ ms_g, float* __restrict__ ks_g)
{
    __shared__ float spk_l[B_*32];
    __shared__ float ms_l[20];
    const int tid = threadIdx.x;
    for(int i=tid; i<B_*32; i+=256){
        int b = i >> 5, j = i & 31;
        float v = spk_embed[speaker[b]*32 + j];
        spk_l[i] = v; spk_sel[i] = v;
    }
    if(tid < 20){
        int n = tid >> 1, j = tid & 1;
        float v = st[n*2]*Ws_pre[j] + st[n*2+1]*Ws_pre[2+j] + bs_pre[j];
        v = fmaxf(v, 0.f);
        ms_l[tid] = v; ms_g[tid] = v;
    }
    __syncthreads();
    if(tid < 20){
        int n = tid >> 1, j = tid & 1;
        ks_g[tid] = ms_l[n*2]*Wk_s[j] + ms_l[n*2+1]*Wk_s[2+j];
    }
    for(int i=tid; i<B_*256; i+=256){
        int b = i >> 8, n = i & 255;
        float acc = ba[n];
        #pragma unroll
        for(int k=0;k<32;++k) acc = fmaf(spk_l[b*32+k], Wa[(256+k)*256 + n], acc);
        aco_spk[i] = acc;
    }
}

// ---------------- K4: keys = enc @ Wk -> bf16 permuted for scan ----------------
__global__ __launch_bounds__(256) void k_keys(const float* __restrict__ enc,
                                              const float* __restrict__ Wk,
                                              ushort_t* __restrict__ keysp){
    __shared__ float x16[16][256];
    const int bid = blockIdx.x;      // 256 = 32 b * 8 tgroups
    const int b = bid >> 3, tg = bid & 7, t0 = tg*16;
    const int tid = threadIdx.x;
    for(int i=tid; i<16*256; i+=256){
        int r = i >> 8, k = i & 255;
        x16[r][k] = enc[((size_t)b*TIN_ + t0 + r)*256 + k];
    }
    __syncthreads();
    float acc[16];
    #pragma unroll
    for(int r=0;r<16;++r) acc[r] = 0.f;
    for(int k=0;k<256;++k){
        float w = Wk[k*256 + tid];
        #pragma unroll
        for(int r=0;r<16;++r) acc[r] = fmaf(x16[r][k], w, acc[r]);
    }
    #pragma unroll
    for(int r=0;r<16;++r){
        int t = t0 + r;
        keysp[((size_t)((t>>2)*32 + b)*4 + (t&3))*256 + tid] = f2bf(acc[r]);
    }
}

// ---------------- enc permute: enc_p[d>>3][b][t][d&7] ----------------
__global__ __launch_bounds__(256) void k_encperm(const float* __restrict__ enc,
                                                 ushort_t* __restrict__ encp){
    int o = blockIdx.x*256 + threadIdx.x;      // 4096 blocks -> 1,048,576
    int j = o & 7, t = (o>>3) & 127, b = (o>>10) & 31, wg = o >> 15;
    encp[o] = f2bf(enc[((size_t)b*TIN_ + t)*256 + wg*8 + j]);
}

// ---------------- K3: prenet + x-part of att-GRU for all steps ----------------
__global__ __launch_bounds__(256) void k_prenet(
    const float* __restrict__ mg, const float* __restrict__ spk_sel,
    const float* __restrict__ Wp1, const float* __restrict__ bp1,
    const float* __restrict__ Wp2, const float* __restrict__ bp2,
    const float* __restrict__ Wg_att, const float* __restrict__ bg_att,
    const float* __restrict__ Wc_att, const float* __restrict__ bc_att,
    float* __restrict__ preg, float* __restrict__ prec)
{
    __shared__ float fr[16][128];
    __shared__ float p1[16][256];
    __shared__ float p2[16][128];
    __shared__ float spk_l[16][32];
    const int r0 = blockIdx.x * 16;     // 200 blocks * 16 rows = 3200 (s*32+b)
    const int tid = threadIdx.x;
    for(int i=tid; i<16*128; i+=256){
        int r = i >> 7, mcol = i & 127;
        int row = r0 + r, s = row >> 5, b = row & 31;
        fr[r][mcol] = (s == 0) ? 0.f : mg[((size_t)b*TOUT_ + s*R_ - 1)*MEL_ + mcol];
    }
    for(int i=tid; i<16*32; i+=256){
        int r = i >> 5, j = i & 31;
        spk_l[r][j] = spk_sel[((r0 + r) & 31)*32 + j];
    }
    __syncthreads();
    {
        float acc[16];
        #pragma unroll
        for(int r=0;r<16;++r) acc[r]=0.f;
        for(int k=0;k<128;++k){
            float w = Wp1[k*256 + tid];
            #pragma unroll
            for(int r=0;r<16;++r) acc[r] = fmaf(fr[r][k], w, acc[r]);
        }
        float bb = bp1[tid];
        #pragma unroll
        for(int r=0;r<16;++r) p1[r][tid] = fmaxf(acc[r] + bb, 0.f);
    }
    __syncthreads();
    if(tid < 128){
        float acc[16];
        #pragma unroll
        for(int r=0;r<16;++r) acc[r]=0.f;
        for(int k=0;k<256;++k){
            float w = Wp2[k*128 + tid];
            #pragma unroll
            for(int r=0;r<16;++r) acc[r] = fmaf(p1[r][k], w, acc[r]);
        }
        float bb = bp2[tid];
        #pragma unroll
        for(int r=0;r<16;++r) p2[r][tid] = fmaxf(acc[r] + bb, 0.f);
    }
    __syncthreads();
    {
        float aA[16], aB[16];
        #pragma unroll
        for(int r=0;r<16;++r){ aA[r]=0.f; aB[r]=0.f; }
        for(int k=0;k<128;++k){
            float wA = Wg_att[k*512 + tid], wB = Wg_att[k*512 + tid + 256];
            #pragma unroll
            for(int r=0;r<16;++r){ float pv = p2[r][k]; aA[r]=fmaf(pv,wA,aA[r]); aB[r]=fmaf(pv,wB,aB[r]); }
        }
        for(int k=0;k<32;++k){
            float wA = Wg_att[(128+k)*512 + tid], wB = Wg_att[(128+k)*512 + tid + 256];
            #pragma unroll
            for(int r=0;r<16;++r){ float sv = spk_l[r][k]; aA[r]=fmaf(sv,wA,aA[r]); aB[r]=fmaf(sv,wB,aB[r]); }
        }
        float bA = bg_att[tid], bB = bg_att[tid + 256];
        #pragma unroll
        for(int r=0;r<16;++r){
            preg[(size_t)(r0+r)*512 + tid]       = aA[r] + bA;
            preg[(size_t)(r0+r)*512 + tid + 256] = aB[r] + bB;
        }
    }
    {
        float acc[16];
        #pragma unroll
        for(int r=0;r<16;++r) acc[r]=0.f;
        for(int k=0;k<128;++k){
            float w = Wc_att[k*256 + tid];
            #pragma unroll
            for(int r=0;r<16;++r) acc[r] = fmaf(p2[r][k], w, acc[r]);
        }
        for(int k=0;k<32;++k){
            float w = Wc_att[(128+k)*256 + tid];
            #pragma unroll
            for(int r=0;r<16;++r) acc[r] = fmaf(spk_l[r][k], w, acc[r]);
        }
        float bb = bc_att[tid];
        #pragma unroll
        for(int r=0;r<16;++r) prec[(size_t)(r0+r)*256 + tid] = acc[r] + bb;
    }
}

// ---------------- cooperative scan helpers ----------------
// Fence-free barrier: per-wave store-drain (sc1 stores are write-through to
// LLC), flag store + relaxed polls at LLC. Cached read-only data stays in L2.
__device__ __forceinline__ void gridbar(int* slots, int p, int seq, int tid){
    asm volatile("s_waitcnt vmcnt(0)" ::: "memory");
    __syncthreads();
    if(tid == 0)
        __hip_atomic_store(&slots[p*32], seq, __ATOMIC_RELAXED, __HIP_MEMORY_SCOPE_AGENT);
    if(tid < NWG_){
        while(__hip_atomic_load(&slots[tid*32], __ATOMIC_RELAXED, __HIP_MEMORY_SCOPE_AGENT) < seq)
            __builtin_amdgcn_s_sleep(1);
    }
    __syncthreads();
}

// load weight col-slice (bf16, col-major [16][Ktot], XOR-swizzled) into LDS
__device__ __forceinline__ void loadW(const float* W, int ldw, int rowbase, int nk, int kbase,
                                      int Ktot, int col0, int ncols, ushort_t* lds, int tid){
    for(int e = tid; e < 16*nk; e += 512){
        int col = e & 15, k = e >> 4;
        ushort_t v = 0;
        if(col < ncols) v = f2bf(W[(size_t)(rowbase + k)*ldw + col0 + col]);
        lds[(col*Ktot + kbase + k) ^ ((col & 7) << 3)] = v;
    }
}

// GEMM: C[32][Ns] += A[32][K] (LLC bf16, grouped ld8 prefetch) * W (LDS swz)
template<int K>
__device__ __forceinline__ f32x4 do_gemm(const ushort_t* Ab, const ushort_t* Wl, float* red,
                                         int m, int kq, int lane){
    const int row = m*16 + (lane & 15);
    const int col = lane & 15;
    const int ko  = (lane >> 4) * 8;
    u64 av[K/64];
    #pragma unroll
    for(int t = 0; t < K/128; ++t){
        const int k0 = kq*(K/4) + t*32 + ko;
        av[2*t]   = ld8(Ab + row*K + k0);
        av[2*t+1] = ld8(Ab + row*K + k0 + 4);
    }
    f32x4 acc = {0.f,0.f,0.f,0.f};
    #pragma unroll
    for(int t = 0; t < K/128; ++t){
        const int k0 = kq*(K/4) + t*32 + ko;
        union { u64 q[2]; bf16x8 v; } ua;
        ua.q[0] = av[2*t]; ua.q[1] = av[2*t+1];
        bf16x8 b = *reinterpret_cast<const bf16x8*>(Wl + ((col*K + k0) ^ ((col & 7) << 3)));
        acc = __builtin_amdgcn_mfma_f32_16x16x32_bf16(ua.v, b, acc, 0, 0, 0);
    }
    if(kq > 0) *reinterpret_cast<f32x4*>(red + ((kq-1)*2 + m)*256 + lane*4) = acc;
    __syncthreads();
    if(kq == 0){
        #pragma unroll
        for(int j = 0; j < 3; ++j)
            acc += *reinterpret_cast<const f32x4*>(red + (j*2 + m)*256 + lane*4);
    }
    return acc;
}

// ---------------- K5: the cooperative scan ----------------
__global__ __launch_bounds__(512) void k_scan_coop(
    char* ws,
    const float* __restrict__ Wg_att, const float* __restrict__ Wc_att,
    const float* __restrict__ Wq, const float* __restrict__ Wq_s,
    const float* __restrict__ v_att, const float* __restrict__ v_s,
    const float* __restrict__ Wa,
    const float* __restrict__ Wg1, const float* __restrict__ Wc1,
    const float* __restrict__ Wg2, const float* __restrict__ Wc2,
    const float* __restrict__ bg1, const float* __restrict__ bc1,
    const float* __restrict__ bg2, const float* __restrict__ bc2,
    const int* __restrict__ inp_mask, float* __restrict__ out_alpha)
{
    const int p = blockIdx.x, tid = threadIdx.x;
    const int lane = tid & 63, wv = tid >> 6;
    const int m = wv & 1, kq = wv >> 1;

    int* slots       = (int*)(ws + ZB_SLOTS);
    ushort_t* A_h    = (ushort_t*)(ws + ZB_AH);
    ushort_t* A_rh   = (ushort_t*)(ws + ZB_ARH);
    ushort_t* A_hc   = (ushort_t*)(ws + ZB_AHC);
    ushort_t* A_xh1  = (ushort_t*)(ws + ZB_AXH1);
    ushort_t* A_xrh1 = (ushort_t*)(ws + ZB_AXRH1);
    ushort_t* A_y1h2 = (ushort_t*)(ws + ZB_AY1H2);
    ushort_t* A_y1rh2= (ushort_t*)(ws + ZB_AY1RH2);
    ushort_t* Qbuf   = (ushort_t*)(ws + ZB_QBUF);
    float* ubuf  = (float*)(ws + ZB_UBUF);
    float* u1buf = (float*)(ws + ZB_U1BUF);
    float* u2buf = (float*)(ws + ZB_U2BUF);
    float* ebuf  = (float*)(ws + ZB_EBUF);
    float* qsbuf = (float*)(ws + ZB_QSBUF);
    const float* acospk = (const float*)(ws + OFF_ACOSPK2);
    const float* msg    = (const float*)(ws + OFF_MS2);
    const float* ksg    = (const float*)(ws + OFF_KS2);
    const float* preg   = (const float*)(ws + OFF_PREG2);
    const float* prec   = (const float*)(ws + OFF_PREC2);
    float* y2g          = (float*)(ws + OFF_Y2G);
    const ushort_t* keysp = (const ushort_t*)(ws + OFF_KEYSP);
    const ushort_t* encp  = (const ushort_t*)(ws + OFF_ENCP);

    // LDS: resident weight slices (col-major [16][K], bf16, swizzled)
    __shared__ ushort_t wA[16*256], wB[16*256], wC[16*256];
    __shared__ ushort_t wG[16*512], wH[16*512], wI[16*512], wJ[16*512], wK[16*512];
    __shared__ __align__(16) char uni[16384];  // red(6K) | qlds(16K) | stg(@8K) | stgf(@10K)
    float* red = (float*)uni;
    ushort_t* qlds = (ushort_t*)uni;
    ushort_t* stg  = (ushort_t*)(uni + 8192);   // [32][16] bf16 pack tile
    float*    stgf = (float*)(uni + 10240);     // [32][16] f32 pack tile
    __shared__ float vatt_l[256];
    __shared__ float msks[48];
    __shared__ float ctxs_l[64];
    __shared__ float acosl[256], acofl[256], y1fl[256];
    __shared__ float hfl[256], h1fl[256], h2fl[256];   // WG-private f32 state masters
    __shared__ float bg1s[16], bc1s[8], bg2s[16], bc2s[8], wasl[16];
    __shared__ float wqs_l[512];
    __shared__ int   maskl[32];

    loadW(Wg_att, 512, 160, 256, 0, 256, p*16, 16, wA, tid);
    loadW(Wc_att, 256, 160, 256, 0, 256, p*8,  8,  wB, tid);
    loadW(Wq,     256, 0,   256, 0, 256, p*8,  8,  wC, tid);
    loadW(Wa,     256, 0,   256, 0,   512, p*8, 8, wG, tid);   // rows 0..255  (h)
    loadW(Wa,     256, 288, 256, 256, 512, p*8, 8, wG, tid);   // rows 288..543 (ctx)
    loadW(Wg1,    512, 0,   512, 0, 512, p*16, 16, wH, tid);
    loadW(Wc1,    256, 0,   512, 0, 512, p*8,  8,  wI, tid);
    loadW(Wg2,    512, 0,   512, 0, 512, p*16, 16, wJ, tid);
    loadW(Wc2,    256, 0,   512, 0, 512, p*8,  8,  wK, tid);
    if(tid < 256){
        vatt_l[tid] = v_att[tid];
        acosl[tid]  = acospk[(tid>>3)*256 + p*8 + (tid&7)];
        hfl[tid] = 0.f; h1fl[tid] = 0.f; h2fl[tid] = 0.f;
    }
    wqs_l[tid] = Wq_s[tid];
    if(tid < 20) msks[tid] = msg[tid];
    if(tid >= 20 && tid < 40) msks[tid] = ksg[tid-20];
    if(tid == 40) msks[40] = v_s[0];
    if(tid == 41) msks[41] = v_s[1];
    if(tid < 16){ bg1s[tid] = bg1[p*16+tid]; bg2s[tid] = bg2[p*16+tid]; }
    if(tid < 8){ bc1s[tid] = bc1[p*8+tid]; bc2s[tid] = bc2[p*8+tid]; }
    if(tid < 16) wasl[tid] = Wa[(size_t)(544 + (tid & 1))*256 + p*8 + (tid >> 1)];
    if(tid < 32) maskl[tid] = inp_mask[tid];
    __syncthreads();

    int seq = 0;
    for(int s = 0; s < STEPS_; ++s){
        const int sb = s*32;
        const int col = lane & 15;
        const int bbase = m*16 + ((lane>>4)<<2);
        // ---- A: att-GRU gates ----
        __syncthreads();   // red WAR guard vs stage K
        u64 hpre[4];
        if(kq == 0 && p < 16){
            #pragma unroll
            for(int r=0;r<4;++r) hpre[r] = ld8(A_h + (bbase+r)*256 + ((p*16+col) & ~3));
        }
        f32x4 acc = do_gemm<256>(A_h, wA, red, m, kq, lane);
        if(kq == 0){
            const int gcol = p*16 + col;
            if(p < 16){
                #pragma unroll
                for(int r=0;r<4;++r){
                    int b = bbase + r;
                    float g = sigm_f(acc[r] + preg[(size_t)(sb + b)*512 + gcol]);
                    float hb = bf1((ushort_t)(hpre[r] >> ((col & 3)*16)));
                    stg[b*16 + col] = f2bf(g * hb);
                }
                CBAR();
                int c = lane, row2 = m*16 + (c>>2), cg = c & 3;
                st8(A_rh + row2*256 + p*16 + cg*4, pack4(stg + row2*16 + cg*4));
            } else {
                #pragma unroll
                for(int r=0;r<4;++r){
                    int b = bbase + r;
                    stgf[b*16 + col] = sigm_f(acc[r] + preg[(size_t)(sb + b)*512 + gcol]);
                }
                CBAR();
                #pragma unroll
                for(int j=0;j<2;++j){
                    int c = lane*2 + j, row2 = m*16 + (c>>3), cg = c & 7;
                    st8(ubuf + row2*256 + (p-16)*16 + cg*2, pack2f(stgf + row2*16 + cg*2));
                }
            }
        }
        gridbar(slots, p, ++seq, tid);
        // ---- B: att-GRU candidate + h update ----
        float upre[4];
        if(kq == 0 && col < 8){
            #pragma unroll
            for(int r=0;r<4;++r) upre[r] = ld4f(ubuf + (bbase+r)*256 + p*8 + col);
        }
        acc = do_gemm<256>(A_rh, wB, red, m, kq, lane);
        if(kq == 0){
            if(col < 8){
                const int gcol = p*8 + col;
                #pragma unroll
                for(int r=0;r<4;++r){
                    int b = bbase + r;
                    float cc = tanh_f(acc[r] + prec[(size_t)(sb + b)*256 + gcol]);
                    float u  = upre[r];
                    float hn = u*hfl[b*8 + col] + (1.f - u)*cc;
                    hfl[b*8 + col] = hn;
                    stg[b*8 + col] = f2bf(hn);
                }
            }
            CBAR();
            if(lane < 32){
                int c = lane, row2 = m*16 + (c>>1), cg = c & 1;
                u64 v = pack4(stg + row2*8 + cg*4);
                st8(A_h  + row2*256 + p*8 + cg*4, v);
                st8(A_hc + row2*512 + p*8 + cg*4, v);
            }
        }
        gridbar(slots, p, ++seq, tid);
        // ---- C: qW = h @ Wq (+ style query on p0, bf16 h from A_h) ----
        acc = do_gemm<256>(A_h, wC, red, m, kq, lane);
        if(kq == 0){
            if(col < 8){
                #pragma unroll
                for(int r=0;r<4;++r) stg[(bbase+r)*8 + col] = f2bf(acc[r]);
            }
            CBAR();
            if(lane < 32){
                int c = lane, row2 = m*16 + (c>>1), cg = c & 1;
                st8(Qbuf + row2*256 + p*8 + cg*4, pack4(stg + row2*8 + cg*4));
            }
        }
        if(p == 0){
            int b = tid >> 4, i = tid & 15;
            float q0 = 0.f, q1 = 0.f;
            #pragma unroll
            for(int jc=0;jc<4;++jc){
                u64 h4 = ld8(A_h + b*256 + i*16 + jc*4);
                #pragma unroll
                for(int j=0;j<4;++j){
                    int k = i*16 + jc*4 + j;
                    float hv = bf1((ushort_t)(h4 >> (j*16)));
                    q0 = fmaf(hv, wqs_l[k*2],   q0);
                    q1 = fmaf(hv, wqs_l[k*2+1], q1);
                }
            }
            #pragma unroll
            for(int d=1; d<16; d<<=1){ q0 += __shfl_xor(q0,d,64); q1 += __shfl_xor(q1,d,64); }
            if(i == 0){
                union{ float f[2]; u64 q; } pr; pr.f[0]=q0; pr.f[1]=q1;
                st8(qsbuf + b*2, pr.q);
            }
        }
        gridbar(slots, p, ++seq, tid);
        // ---- D: attention scores (t-slice of 4 per WG; keys L2-cached) ----
        {
            u64* ql = (u64*)qlds;
            const u64* Qb = (const u64*)Qbuf;
            #pragma unroll
            for(int j=0;j<4;++j) ql[tid + j*512] = ld8(Qb + tid + j*512);
        }
        __syncthreads();
        {
            int b = tid >> 4, tl = (tid >> 2) & 3, q = tid & 3;
            int tg = p*4 + tl;
            const ushort_t* kp = keysp + (((size_t)p*32 + b)*4 + tl)*256 + q*64;
            const ushort_t* qp = qlds + b*256 + q*64;
            float e = 0.f;
            #pragma unroll
            for(int i2=0;i2<8;++i2){
                bf16x8 kv = *(const bf16x8*)(kp + i2*8);
                bf16x8 qv = *(const bf16x8*)(qp + i2*8);
                #pragma unroll
                for(int j=0;j<8;++j){
                    int a = q*64 + i2*8 + j;
                    e = fmaf(vatt_l[a], tanh_f(bf1((ushort_t)kv[j]) + bf1((ushort_t)qv[j])), e);
                }
            }
            e += __shfl_xor(e, 1, 64); e += __shfl_xor(e, 2, 64);
            if(q == 0) st4f(ebuf + b*128 + tg, (tg < maskl[b]) ? e : -1e9f);
        }
        gridbar(slots, p, ++seq, tid);
        // ---- E: redundant softmax + context col-slice + style ctx ----
        {
            int b = tid >> 4, i = tid & 15;
            u64 ea = ld8(ebuf + b*128 + i*8);
            u64 eb = ld8(ebuf + b*128 + i*8 + 2);
            u64 ec = ld8(ebuf + b*128 + i*8 + 4);
            u64 ed = ld8(ebuf + b*128 + i*8 + 6);
            float ev[8] = { u64lo(ea),u64hi(ea),u64lo(eb),u64hi(eb),
                            u64lo(ec),u64hi(ec),u64lo(ed),u64hi(ed) };
            float mx = ev[0];
            #pragma unroll
            for(int j=1;j<8;++j) mx = fmaxf(mx, ev[j]);
            #pragma unroll
            for(int d=1; d<16; d<<=1) mx = fmaxf(mx, __shfl_xor(mx,d,64));
            float a8[8]; float sum = 0.f;
            #pragma unroll
            for(int j=0;j<8;++j){ a8[j] = fexp2((ev[j]-mx)*1.44269504f); sum += a8[j]; }
            #pragma unroll
            for(int d=1; d<16; d<<=1) sum += __shfl_xor(sum,d,64);
            float inv = frcp(sum);
            #pragma unroll
            for(int j=0;j<8;++j) a8[j] *= inv;
            if(p == 1){
                float* oa = out_alpha + ((size_t)b*STEPS_ + s)*TIN_ + i*8;
                #pragma unroll
                for(int j=0;j<8;++j) oa[j] = a8[j];
            }
            float cj[8] = {0,0,0,0,0,0,0,0};
            const ushort_t* ep = encp + (((size_t)p*32 + b)*128 + i*8)*8;
            #pragma unroll
            for(int t2=0;t2<8;++t2){
                bf16x8 ev2 = *(const bf16x8*)(ep + t2*8);
                #pragma unroll
                for(int j=0;j<8;++j) cj[j] = fmaf(a8[t2], bf1((ushort_t)ev2[j]), cj[j]);
            }
            #pragma unroll
            for(int d=1; d<16; d<<=1){
                #pragma unroll
                for(int j=0;j<8;++j) cj[j] += __shfl_xor(cj[j],d,64);
            }
            if(i == 0){
                union{ ushort_t s4[4]; u64 q; } pk0, pk1;
                #pragma unroll
                for(int j=0;j<4;++j){ pk0.s4[j] = f2bf(cj[j]); pk1.s4[j] = f2bf(cj[4+j]); }
                st8(A_hc + b*512 + 256 + p*8,     pk0.q);
                st8(A_hc + b*512 + 256 + p*8 + 4, pk1.q);
            }
        }
        if(tid < 32){
            int b = tid;
            u64 qq = ld8(qsbuf + b*2);
            float q0 = u64lo(qq), q1 = u64hi(qq);
            float es[10]; float mx = -1e30f;
            #pragma unroll
            for(int n=0;n<10;++n){
                float t = msks[40]*tanh_f(msks[20+n*2] + q0) + msks[41]*tanh_f(msks[20+n*2+1] + q1);
                es[n] = t; mx = fmaxf(mx, t);
            }
            float sum = 0.f;
            #pragma unroll
            for(int n=0;n<10;++n){ float pe = fexp2((es[n]-mx)*1.44269504f); es[n]=pe; sum += pe; }
            float inv = frcp(sum); float c0=0.f, c1=0.f;
            #pragma unroll
            for(int n=0;n<10;++n){ float al = es[n]*inv; c0 = fmaf(al, msks[n*2], c0); c1 = fmaf(al, msks[n*2+1], c1); }
            ctxs_l[b*2] = c0; ctxs_l[b*2+1] = c1;
        }
        gridbar(slots, p, ++seq, tid);
        // ---- G: aco = [h|ctx]@Wa + acospk + ctx_s@Wa_s ----
        acc = do_gemm<512>(A_hc, wG, red, m, kq, lane);
        if(kq == 0){
            if(col < 8){
                #pragma unroll
                for(int r=0;r<4;++r){
                    int b = bbase + r;
                    float v = acc[r] + acosl[b*8 + col]
                            + ctxs_l[b*2]   * wasl[col*2]
                            + ctxs_l[b*2+1] * wasl[col*2+1];
                    acofl[b*8 + col] = v;
                    stg[b*8 + col] = f2bf(v);
                }
            }
            CBAR();
            if(lane < 32){
                int c = lane, row2 = m*16 + (c>>1), cg = c & 1;
                u64 v = pack4(stg + row2*8 + cg*4);
                st8(A_xh1  + row2*512 + p*8 + cg*4, v);
                st8(A_xrh1 + row2*512 + p*8 + cg*4, v);
            }
        }
        gridbar(slots, p, ++seq, tid);
        // ---- H: GRU1 gates ----
        if(kq == 0 && p < 16){
            #pragma unroll
            for(int r=0;r<4;++r) hpre[r] = ld8(A_xh1 + (bbase+r)*512 + 256 + ((p*16+col) & ~3));
        }
        acc = do_gemm<512>(A_xh1, wH, red, m, kq, lane);
        if(kq == 0){
            if(p < 16){
                #pragma unroll
                for(int r=0;r<4;++r){
                    int b = bbase + r;
                    float g = sigm_f(acc[r] + bg1s[col]);
                    float hb = bf1((ushort_t)(hpre[r] >> ((col & 3)*16)));
                    stg[b*16 + col] = f2bf(g * hb);
                }
                CBAR();
                int c = lane, row2 = m*16 + (c>>2), cg = c & 3;
                st8(A_xrh1 + row2*512 + 256 + p*16 + cg*4, pack4(stg + row2*16 + cg*4));
            } else {
                #pragma unroll
                for(int r=0;r<4;++r)
                    stgf[(bbase+r)*16 + col] = sigm_f(acc[r] + bg1s[col]);
                CBAR();
                #pragma unroll
                for(int j=0;j<2;++j){
                    int c = lane*2 + j, row2 = m*16 + (c>>3), cg = c & 7;
                    st8(u1buf + row2*256 + (p-16)*16 + cg*2, pack2f(stgf + row2*16 + cg*2));
                }
            }
        }
        gridbar(slots, p, ++seq, tid);
        // ---- I: GRU1 candidate + y1 ----
        if(kq == 0 && col < 8){
            #pragma unroll
            for(int r=0;r<4;++r) upre[r] = ld4f(u1buf + (bbase+r)*256 + p*8 + col);
        }
        acc = do_gemm<512>(A_xrh1, wI, red, m, kq, lane);
        if(kq == 0){
            if(col < 8){
                #pragma unroll
                for(int r=0;r<4;++r){
                    int b = bbase + r;
                    float cc = tanh_f(acc[r] + bc1s[col]);
                    float u  = upre[r];
                    float hn = u*h1fl[b*8 + col] + (1.f - u)*cc;
                    h1fl[b*8 + col] = hn;
                    stg[b*8 + col] = f2bf(hn);
                    float y1 = hn + acofl[b*8 + col];
                    y1fl[b*8 + col] = y1;
                    stg[256 + b*8 + col] = f2bf(y1);
                }
            }
            CBAR();
            if(lane < 32){
                int c = lane, row2 = m*16 + (c>>1), cg = c & 1;
                u64 vh = pack4(stg + row2*8 + cg*4);
                u64 vy = pack4(stg + 256 + row2*8 + cg*4);
                st8(A_xh1   + row2*512 + 256 + p*8 + cg*4, vh);
                st8(A_y1h2  + row2*512 + p*8 + cg*4, vy);
                st8(A_y1rh2 + row2*512 + p*8 + cg*4, vy);
            }
        }
        gridbar(slots, p, ++seq, tid);
        // ---- J: GRU2 gates ----
        if(kq == 0 && p < 16){
            #pragma unroll
            for(int r=0;r<4;++r) hpre[r] = ld8(A_y1h2 + (bbase+r)*512 + 256 + ((p*16+col) & ~3));
        }
        acc = do_gemm<512>(A_y1h2, wJ, red, m, kq, lane);
        if(kq == 0){
            if(p < 16){
                #pragma unroll
                for(int r=0;r<4;++r){
                    int b = bbase + r;
                    float g = sigm_f(acc[r] + bg2s[col]);
                    float hb = bf1((ushort_t)(hpre[r] >> ((col & 3)*16)));
                    stg[b*16 + col] = f2bf(g * hb);
                }
                CBAR();
                int c = lane, row2 = m*16 + (c>>2), cg = c & 3;
                st8(A_y1rh2 + row2*512 + 256 + p*16 + cg*4, pack4(stg + row2*16 + cg*4));
            } else {
                #pragma unroll
                for(int r=0;r<4;++r)
                    stgf[(bbase+r)*16 + col] = sigm_f(acc[r] + bg2s[col]);
                CBAR();
                #pragma unroll
                for(int j=0;j<2;++j){
                    int c = lane*2 + j, row2 = m*16 + (c>>3), cg = c & 7;
                    st8(u2buf + row2*256 + (p-16)*16 + cg*2, pack2f(stgf + row2*16 + cg*2));
                }
            }
        }
        gridbar(slots, p, ++seq, tid);
        // ---- K: GRU2 candidate + y2 (no barrier; loop-top syncthreads guards red) ----
        if(kq == 0 && col < 8){
            #pragma unroll
            for(int r=0;r<4;++r) upre[r] = ld4f(u2buf + (bbase+r)*256 + p*8 + col);
        }
        acc = do_gemm<512>(A_y1rh2, wK, red, m, kq, lane);
        if(kq == 0){
            if(col < 8){
                const int gcol = p*8 + col;
                #pragma unroll
                for(int r=0;r<4;++r){
                    int b = bbase + r;
                    float cc = tanh_f(acc[r] + bc2s[col]);
                    float u  = upre[r];
                    float hn = u*h2fl[b*8 + col] + (1.f - u)*cc;
                    h2fl[b*8 + col] = hn;
                    stg[b*8 + col] = f2bf(hn);
                    y2g[((size_t)sb + b)*256 + gcol] = hn + y1fl[b*8 + col];
                }
            }
            CBAR();
            if(lane < 32){
                int c = lane, row2 = m*16 + (c>>1), cg = c & 1;
                st8(A_y1h2 + row2*512 + 256 + p*8 + cg*4, pack4(stg + row2*8 + cg*4));
            }
        }
    }
}

// ---------------- K6: output_mel = y2 @ Wo + bo ----------------
__global__ __launch_bounds__(256) void k_omel(const float* __restrict__ y2g,
                                              const float* __restrict__ Wo,
                                              const float* __restrict__ bo,
                                              float* __restrict__ out_mel){
    __shared__ float y8[8][256];
    const int r0 = blockIdx.x * 8;
    const int tid = threadIdx.x;
    for(int i=tid; i<8*256; i+=256){ int r=i>>8, k=i&255; y8[r][k] = y2g[(size_t)(r0+r)*256 + k]; }
    __syncthreads();
    float aA[8], aB[8], aC[8];
    #pragma unroll
    for(int r=0;r<8;++r){ aA[r]=0.f; aB[r]=0.f; aC[r]=0.f; }
    for(int k=0;k<256;++k){
        float wA = Wo[(size_t)k*640 + tid];
        float wB = Wo[(size_t)k*640 + tid + 256];
        float wC = (tid < 128) ? Wo[(size_t)k*640 + tid + 512] : 0.f;
        #pragma unroll
        for(int r=0;r<8;++r){
            float yv = y8[r][k];
            aA[r]=fmaf(yv,wA,aA[r]); aB[r]=fmaf(yv,wB,aB[r]); aC[r]=fmaf(yv,wC,aC[r]);
        }
    }
    float bA = bo[tid], bB = bo[tid+256], bC = (tid<128)? bo[tid+512] : 0.f;
    #pragma unroll
    for(int r=0;r<8;++r){
        int row = r0 + r, s = row >> 5, b = row & 31;
        int mm = tid & 127;
        out_mel[((size_t)b*TOUT_ + s*R_ + (tid>>7))*MEL_ + mm]     = aA[r] + bA;
        out_mel[((size_t)b*TOUT_ + s*R_ + 2 + (tid>>7))*MEL_ + mm] = aB[r] + bB;
        if(tid < 128)
            out_mel[((size_t)b*TOUT_ + s*R_ + 4)*MEL_ + tid]       = aC[r] + bC;
    }
}

// ---------------- K7: output_spec = mel @ Wspec + bspec ----------------
__global__ __launch_bounds__(256) void k_spec(const float* __restrict__ out_mel,
                                              const float* __restrict__ Wspec,
                                              const float* __restrict__ bspec,
                                              float* __restrict__ out_spec){
    __shared__ float m8[8][128];
    const int r0 = blockIdx.x * 8;
    const int tid = threadIdx.x;
    for(int i=tid; i<8*128; i+=256){ int r=i>>7, k=i&127; m8[r][k] = out_mel[(size_t)(r0+r)*128 + k]; }
    __syncthreads();
    float aA[8], aB[8], aC[8];
    #pragma unroll
    for(int r=0;r<8;++r){ aA[r]=0.f; aB[r]=0.f; aC[r]=0.f; }
    for(int k=0;k<128;++k){
        float wA = Wspec[(size_t)k*SPEC_ + tid];
        float wB = Wspec[(size_t)k*SPEC_ + 256 + tid];
        float wC = (tid == 0) ? Wspec[(size_t)k*SPEC_ + 512] : 0.f;
        #pragma unroll
        for(int r=0;r<8;++r){
            float mv = m8[r][k];
            aA[r]=fmaf(mv,wA,aA[r]); aB[r]=fmaf(mv,wB,aB[r]); aC[r]=fmaf(mv,wC,aC[r]);
        }
    }
    float bA = bspec[tid], bB = bspec[256+tid];
    #pragma unroll
    for(int r=0;r<8;++r){
        size_t row = (size_t)(r0 + r);
        out_spec[row*SPEC_ + tid]       = aA[r] + bA;
        out_spec[row*SPEC_ + 256 + tid] = aB[r] + bB;
        if(tid == 0) out_spec[row*SPEC_ + 512] = aC[r] + bspec[512];
    }
}

// ---------------- launcher ----------------
extern "C" void kernel_launch(void* const* d_in, const int* in_sizes, int n_in,
                              void* d_out, int out_size, void* d_ws, size_t ws_size,
                              hipStream_t stream) {
    const float* enc       = (const float*)d_in[0];
    const float* st        = (const float*)d_in[1];
    const float* mg        = (const float*)d_in[2];
    const int*   speaker   = (const int*)  d_in[3];
    const int*   inp_mask  = (const int*)  d_in[4];
    const float* spk_embed = (const float*)d_in[5];
    const float* Wp1=(const float*)d_in[6],  *bp1=(const float*)d_in[7];
    const float* Wp2=(const float*)d_in[8],  *bp2=(const float*)d_in[9];
    const float* Wg_att=(const float*)d_in[10], *bg_att=(const float*)d_in[11];
    const float* Wc_att=(const float*)d_in[12], *bc_att=(const float*)d_in[13];
    const float* Wk=(const float*)d_in[14], *Wq=(const float*)d_in[15], *v_att=(const float*)d_in[16];
    const float* Ws_pre=(const float*)d_in[17], *bs_pre=(const float*)d_in[18];
    const float* Wk_s=(const float*)d_in[19], *Wq_s=(const float*)d_in[20], *v_s=(const float*)d_in[21];
    const float* Wa=(const float*)d_in[22], *ba=(const float*)d_in[23];
    const float* Wg1=(const float*)d_in[24], *bg1=(const float*)d_in[25];
    const float* Wc1=(const float*)d_in[26], *bc1=(const float*)d_in[27];
    const float* Wg2=(const float*)d_in[28], *bg2=(const float*)d_in[29];
    const float* Wc2=(const float*)d_in[30], *bc2=(const float*)d_in[31];
    const float* Wo=(const float*)d_in[32], *bo=(const float*)d_in[33];
    const float* Wspec=(const float*)d_in[34], *bspec=(const float*)d_in[35];

    float* out       = (float*)d_out;
    float* out_mel   = out;             // 32*500*128
    float* out_spec  = out + 2048000;   // 32*500*513
    float* out_alpha = out + 10256000;  // 32*100*128

    char* ws = (char*)d_ws;
    float*    spk_sel = (float*)(ws + OFF_SPK2);
    float*    aco_spk = (float*)(ws + OFF_ACOSPK2);
    float*    ms_g    = (float*)(ws + OFF_MS2);
    float*    ks_g    = (float*)(ws + OFF_KS2);
    float*    preg    = (float*)(ws + OFF_PREG2);
    float*    prec    = (float*)(ws + OFF_PREC2);
    float*    y2g     = (float*)(ws + OFF_Y2G);
    ushort_t* keysp   = (ushort_t*)(ws + OFF_KEYSP);
    ushort_t* encp    = (ushort_t*)(ws + OFF_ENCP);

    hipMemsetAsync(d_ws, 0, ZB_END, stream);

    k_small<<<dim3(1), dim3(256), 0, stream>>>(st, Ws_pre, bs_pre, Wk_s, spk_embed,
                                               speaker, Wa, ba, spk_sel, aco_spk, ms_g, ks_g);
    k_keys   <<<dim3(256),  dim3(256), 0, stream>>>(enc, Wk, keysp);
    k_encperm<<<dim3(4096), dim3(256), 0, stream>>>(enc, encp);
    k_prenet <<<dim3(200),  dim3(256), 0, stream>>>(mg, spk_sel, Wp1, bp1, Wp2, bp2,
                                                    Wg_att, bg_att, Wc_att, bc_att, preg, prec);
    k_scan_coop<<<dim3(NWG_), dim3(512), 0, stream>>>(ws, Wg_att, Wc_att, Wq, Wq_s,
                                                      v_att, v_s, Wa, Wg1, Wc1, Wg2, Wc2,
                                                      bg1, bc1, bg2, bc2, inp_mask, out_alpha);
    k_omel <<<dim3(400),  dim3(256), 0, stream>>>(y2g, Wo, bo, out_mel);
    k_spec <<<dim3(2000), dim3(256), 0, stream>>>(out_mel, Wspec, bspec, out_spec);
}